// Round 4
// baseline (279.688 us; speedup 1.0000x reference)
//
#include <hip/hip_runtime.h>
#include <math.h>

// ============================================================================
// Cross-covariance transformer block.  Round 4:
//  - k_qkvs   : fused QKV (split-bf16 MFMA) + group-norm + partial scores
//  - k_medsoft: median mask + softmax -> probs
//  - k_tail   : FUSED AO-gather + Wo GEMM + LN1 + FFN + LN2 (+v).
//               attn/h intermediates never touch HBM (saves ~256 MB).
// Reshape semantics: chunk p = tok/256; row r = tok%256; chan group j;
// output perm tok2 = g*8192 + r*32 + j*2 + b/16, c2 = (b%16)*8 + d.
// For an output tile [T0,T0+64): g = T0>>13, r ∈ {r0,r0+1}; needed V rows:
// t = (g*32 + hb*16 + bm)*256 + r  (64 rows, all 16 chunks -> 16 KB).
// ============================================================================

typedef __bf16 bf16x8 __attribute__((ext_vector_type(8)));
typedef float f32x4 __attribute__((ext_vector_type(4)));
typedef unsigned short u16x8 __attribute__((ext_vector_type(8)));
typedef unsigned int u32x2 __attribute__((ext_vector_type(2)));
typedef unsigned short ushort_t;

static constexpr int  DM   = 128;
static constexpr long NTOK = 131072;                 // B*S = 32*4096
static constexpr float NORMF = 0.17677669529663687f; // 1/sqrt(32)

__device__ __forceinline__ unsigned short f2b(float x) {
    unsigned u = __builtin_bit_cast(unsigned, x);
    return (unsigned short)((u + 0x7fffu + ((u >> 16) & 1u)) >> 16);  // RNE
}
__device__ __forceinline__ float b2f(unsigned short h) {
    return __builtin_bit_cast(float, ((unsigned)h) << 16);
}
__device__ __forceinline__ unsigned pack2(float a, float b) {
    return (unsigned)f2b(a) | ((unsigned)f2b(b) << 16);
}
__device__ __forceinline__ f32x4 mfma16(bf16x8 a, bf16x8 b, f32x4 c) {
    return __builtin_amdgcn_mfma_f32_16x16x32_bf16(a, b, c, 0, 0, 0);
}
// [64][128] bf16 tile, 16B chunks XOR-swizzled by tok&7
__device__ __forceinline__ int xb_off(int tok, int chunk) {
    int c = (chunk & 8) | ((chunk ^ tok) & 7);
    return tok * 128 + c * 8;
}
// [64][256] bf16 tile
__device__ __forceinline__ int h2_off(int tok, int chunk) {
    int c = (chunk & 24) | ((chunk ^ tok) & 7);
    return tok * 256 + c * 8;
}
// gelu via A&S 7.1.26 erf approx (|err| ~1.5e-7)
__device__ __forceinline__ float gelu_f(float x) {
    float t = 0.70710678118654752f * x;
    float s = fabsf(t);
    float u = __builtin_amdgcn_rcpf(fmaf(0.3275911f, s, 1.0f));
    float p = fmaf(fmaf(fmaf(fmaf(1.061405429f, u, -1.453152027f), u,
                             1.421413741f), u, -0.284496736f), u, 0.254829592f);
    p *= u;
    float e = __expf(-s * s);
    float er = fmaf(-p, e, 1.0f);
    er = (t < 0.f) ? -er : er;
    return 0.5f * x * (1.0f + er);
}

// ---------------------------------------------------------------------------
// k_wcvt: weights -> MFMA-A-fragment-linear bf16 (W1/W2/Wo single, Wq/Wk/Wv
// hi/lo split).  A-frag: value = W[k][m], m = ot*16+lr, k = ks*32+lg*8+j.
// ---------------------------------------------------------------------------
__global__ __launch_bounds__(256)
void k_wcvt(const float* __restrict__ W1, const float* __restrict__ W2,
            const float* __restrict__ Wo, const float* __restrict__ Wq,
            const float* __restrict__ Wk, const float* __restrict__ Wv,
            ushort_t* __restrict__ W1t, ushort_t* __restrict__ W2t,
            ushort_t* __restrict__ Wot,
            ushort_t* __restrict__ Wqh, ushort_t* __restrict__ Wql,
            ushort_t* __restrict__ Wkh, ushort_t* __restrict__ Wkl,
            ushort_t* __restrict__ Wvh, ushort_t* __restrict__ Wvl)
{
    int frag = blockIdx.x * 4 + (threadIdx.x >> 6);
    int l = threadIdx.x & 63;
    int lr = l & 15, lg = l >> 4;
    u16x8 v;
    if (frag < 128) {                       // W1t: 32 hcol-tiles x 4 k-steps
        int ht = frag >> 2, ks = frag & 3;
        #pragma unroll
        for (int j = 0; j < 8; ++j)
            v[j] = f2b(W1[(ks * 32 + lg * 8 + j) * 512 + ht * 16 + lr]);
        *(u16x8*)(W1t + ((long)frag * 64 + l) * 8) = v;
    } else if (frag < 256) {                // W2t: 8 oc-tiles x 16 k-steps
        int f = frag - 128;
        int ot = f >> 4, ks = f & 15;
        #pragma unroll
        for (int j = 0; j < 8; ++j)
            v[j] = f2b(W2[(ks * 32 + lg * 8 + j) * 128 + ot * 16 + lr]);
        *(u16x8*)(W2t + ((long)f * 64 + l) * 8) = v;
    } else if (frag < 288) {                // Wot: 8 oc-tiles x 4 k-steps
        int f = frag - 256;
        int ot = f >> 2, ks = f & 3;
        #pragma unroll
        for (int j = 0; j < 8; ++j)
            v[j] = f2b(Wo[(ks * 32 + lg * 8 + j) * 128 + ot * 16 + lr]);
        *(u16x8*)(Wot + ((long)f * 64 + l) * 8) = v;
    } else {                                // Wq/Wk/Wv hi+lo, 32 frags each
        int f = frag - 288;
        const float* S = (f < 32) ? Wq : (f < 64) ? Wk : Wv;
        ushort_t* dh = (f < 32) ? Wqh : (f < 64) ? Wkh : Wvh;
        ushort_t* dl = (f < 32) ? Wql : (f < 64) ? Wkl : Wvl;
        int fl = f & 31, ot = fl >> 2, ks = fl & 3;
        u16x8 vh, vl;
        #pragma unroll
        for (int j = 0; j < 8; ++j) {
            float x = S[(ks * 32 + lg * 8 + j) * 128 + ot * 16 + lr];
            unsigned short h = f2b(x);
            vh[j] = h;
            vl[j] = f2b(x - b2f(h));
        }
        *(u16x8*)(dh + ((long)fl * 64 + l) * 8) = vh;
        *(u16x8*)(dl + ((long)fl * 64 + l) * 8) = vl;
    }
}

// ---------------------------------------------------------------------------
// k_qkvs: 64 tokens/block.  Split-bf16 MFMA for Q (from v), K,V (from q);
// 8-group normalize Q,K; partial scores -> scoreacc[block][64];
// V (bf16) -> global via LDS transpose.
// ---------------------------------------------------------------------------
__global__ __launch_bounds__(256, 2)
void k_qkvs(const float* __restrict__ qin, const float* __restrict__ vin,
            const ushort_t* __restrict__ Wqh, const ushort_t* __restrict__ Wql,
            const ushort_t* __restrict__ Wkh, const ushort_t* __restrict__ Wkl,
            const ushort_t* __restrict__ Wvh, const ushort_t* __restrict__ Wvl,
            const float* __restrict__ bq, const float* __restrict__ bk,
            const float* __restrict__ bv,
            ushort_t* __restrict__ Vbf, float* __restrict__ scoreacc)
{
    __shared__ __align__(16) char smem[65536];
    ushort_t* vhi = (ushort_t*)smem;            // [64][128] swz  (input v)
    ushort_t* vlo = vhi + 8192;
    ushort_t* qhi = vlo + 8192;                 // (input q)
    ushort_t* qlo = qhi + 8192;
    ushort_t* Vt  = (ushort_t*)smem;            // alias (16 KB) after phases
    float*    red = (float*)(smem + 16384);     // [16][33] alias

    const int tid = threadIdx.x;
    const int w = tid >> 6, l = tid & 63;
    const int lr = l & 15, lg = l >> 4;
    const long tok0 = (long)blockIdx.x * 64;

    // ---- stage inputs, split hi/lo ----
    #pragma unroll
    for (int i = 0; i < 4; ++i) {
        int e = tid + i * 256;
        int tok = e >> 4, c = e & 15;
        long base = (tok0 + tok) * DM + c * 8;
        int xo = xb_off(tok, c);
        {
            float4 a0 = *(const float4*)(vin + base);
            float4 a1 = *(const float4*)(vin + base + 4);
            float xs[8] = {a0.x, a0.y, a0.z, a0.w, a1.x, a1.y, a1.z, a1.w};
            u16x8 hi, lo;
            #pragma unroll
            for (int jj = 0; jj < 8; ++jj) {
                unsigned short h = f2b(xs[jj]);
                hi[jj] = h; lo[jj] = f2b(xs[jj] - b2f(h));
            }
            *(u16x8*)(vhi + xo) = hi;
            *(u16x8*)(vlo + xo) = lo;
        }
        {
            float4 a0 = *(const float4*)(qin + base);
            float4 a1 = *(const float4*)(qin + base + 4);
            float xs[8] = {a0.x, a0.y, a0.z, a0.w, a1.x, a1.y, a1.z, a1.w};
            u16x8 hi, lo;
            #pragma unroll
            for (int jj = 0; jj < 8; ++jj) {
                unsigned short h = f2b(xs[jj]);
                hi[jj] = h; lo[jj] = f2b(xs[jj] - b2f(h));
            }
            *(u16x8*)(qhi + xo) = hi;
            *(u16x8*)(qlo + xo) = lo;
        }
    }
    __syncthreads();

    // ---- Q phase (input v) ----
    float qv[2][4][4];
    {
        f32x4 acc[2][4];
        #pragma unroll
        for (int ot = 0; ot < 2; ++ot)
            #pragma unroll
            for (int tt = 0; tt < 4; ++tt) acc[ot][tt] = (f32x4){0,0,0,0};
        #pragma unroll
        for (int ks = 0; ks < 4; ++ks) {
            bf16x8 wh[2], wl[2];
            #pragma unroll
            for (int ot = 0; ot < 2; ++ot) {
                int fi = (((w * 2 + ot) * 4 + ks) * 64 + l) * 8;
                wh[ot] = *(const bf16x8*)(Wqh + fi);
                wl[ot] = *(const bf16x8*)(Wql + fi);
            }
            #pragma unroll
            for (int tt = 0; tt < 4; ++tt) {
                int xo = xb_off(tt * 16 + lr, ks * 4 + lg);
                bf16x8 xh = *(const bf16x8*)(vhi + xo);
                bf16x8 xl = *(const bf16x8*)(vlo + xo);
                #pragma unroll
                for (int ot = 0; ot < 2; ++ot) {
                    acc[ot][tt] = mfma16(wh[ot], xh, acc[ot][tt]);
                    acc[ot][tt] = mfma16(wh[ot], xl, acc[ot][tt]);
                    acc[ot][tt] = mfma16(wl[ot], xh, acc[ot][tt]);
                }
            }
        }
        #pragma unroll
        for (int ot = 0; ot < 2; ++ot) {
            f32x4 bqv = *(const f32x4*)(bq + w * 32 + ot * 16 + lg * 4);
            #pragma unroll
            for (int tt = 0; tt < 4; ++tt) {
                float s2 = 0.f;
                #pragma unroll
                for (int r = 0; r < 4; ++r) {
                    float x = acc[ot][tt][r] + bqv[r];
                    qv[ot][tt][r] = x;
                    s2 = fmaf(x, x, s2);
                }
                s2 += __shfl_xor(s2, 16);
                float inv = 1.0f / fmaxf(sqrtf(s2), 1e-12f);
                #pragma unroll
                for (int r = 0; r < 4; ++r) qv[ot][tt][r] *= inv;
            }
        }
    }

    // ---- K+V phase (input q) + incremental score accumulation ----
    float vv[2][4][4];
    float part[4][8];
    #pragma unroll
    for (int r = 0; r < 4; ++r)
        #pragma unroll
        for (int e = 0; e < 8; ++e) part[r][e] = 0.f;
    {
        f32x4 acck[2][4], accv[2][4];
        #pragma unroll
        for (int ot = 0; ot < 2; ++ot)
            #pragma unroll
            for (int tt = 0; tt < 4; ++tt) {
                acck[ot][tt] = (f32x4){0,0,0,0};
                accv[ot][tt] = (f32x4){0,0,0,0};
            }
        #pragma unroll
        for (int ks = 0; ks < 4; ++ks) {
            bf16x8 whk[2], wlk[2], whv[2], wlv[2];
            #pragma unroll
            for (int ot = 0; ot < 2; ++ot) {
                int fi = (((w * 2 + ot) * 4 + ks) * 64 + l) * 8;
                whk[ot] = *(const bf16x8*)(Wkh + fi);
                wlk[ot] = *(const bf16x8*)(Wkl + fi);
                whv[ot] = *(const bf16x8*)(Wvh + fi);
                wlv[ot] = *(const bf16x8*)(Wvl + fi);
            }
            #pragma unroll
            for (int tt = 0; tt < 4; ++tt) {
                int xo = xb_off(tt * 16 + lr, ks * 4 + lg);
                bf16x8 xh = *(const bf16x8*)(qhi + xo);
                bf16x8 xl = *(const bf16x8*)(qlo + xo);
                #pragma unroll
                for (int ot = 0; ot < 2; ++ot) {
                    acck[ot][tt] = mfma16(whk[ot], xh, acck[ot][tt]);
                    acck[ot][tt] = mfma16(whk[ot], xl, acck[ot][tt]);
                    acck[ot][tt] = mfma16(wlk[ot], xh, acck[ot][tt]);
                    accv[ot][tt] = mfma16(whv[ot], xh, accv[ot][tt]);
                    accv[ot][tt] = mfma16(whv[ot], xl, accv[ot][tt]);
                    accv[ot][tt] = mfma16(wlv[ot], xh, accv[ot][tt]);
                }
            }
        }
        const int h0 = (lg & 1) * 4;
        #pragma unroll
        for (int ot = 0; ot < 2; ++ot) {
            f32x4 bkv = *(const f32x4*)(bk + w * 32 + ot * 16 + lg * 4);
            f32x4 bvv = *(const f32x4*)(bv + w * 32 + ot * 16 + lg * 4);
            #pragma unroll
            for (int tt = 0; tt < 4; ++tt) {
                float kq[4];
                float s2 = 0.f;
                #pragma unroll
                for (int r = 0; r < 4; ++r) {
                    float x = acck[ot][tt][r] + bkv[r];
                    kq[r] = x;
                    s2 = fmaf(x, x, s2);
                    vv[ot][tt][r] = accv[ot][tt][r] + bvv[r];
                }
                s2 += __shfl_xor(s2, 16);
                float inv = 1.0f / fmaxf(sqrtf(s2), 1e-12f);
                #pragma unroll
                for (int r = 0; r < 4; ++r) kq[r] *= inv;
                float ko[4];
                #pragma unroll
                for (int r = 0; r < 4; ++r) ko[r] = __shfl_xor(kq[r], 16);
                float ke[8];
                #pragma unroll
                for (int r = 0; r < 4; ++r) {
                    ke[h0 + r] = kq[r];
                    ke[(h0 ^ 4) + r] = ko[r];
                }
                #pragma unroll
                for (int r = 0; r < 4; ++r)
                    #pragma unroll
                    for (int e = 0; e < 8; ++e)
                        part[r][e] = fmaf(qv[ot][tt][r], ke[e], part[r][e]);
            }
        }
    }
    // reduce partials over lr lanes (bits 0..3)
    #pragma unroll
    for (int r = 0; r < 4; ++r)
        #pragma unroll
        for (int e = 0; e < 8; ++e) {
            float p = part[r][e];
            p += __shfl_xor(p, 1);
            p += __shfl_xor(p, 2);
            p += __shfl_xor(p, 4);
            p += __shfl_xor(p, 8);
            part[r][e] = p;
        }
    __syncthreads();   // x-tiles fully consumed; alias regions now writable

    // V regs -> Vt (swizzled bf16 [64][128])
    #pragma unroll
    for (int ot = 0; ot < 2; ++ot) {
        int oc0 = w * 32 + ot * 16 + lg * 4;
        int ch = oc0 >> 3;
        #pragma unroll
        for (int tt = 0; tt < 4; ++tt) {
            int tok = tt * 16 + lr;
            int cz = (ch & 8) | ((ch ^ tok) & 7);
            u32x2 pk = {pack2(vv[ot][tt][0], vv[ot][tt][1]),
                        pack2(vv[ot][tt][2], vv[ot][tt][3])};
            *(u32x2*)(Vt + tok * 128 + cz * 8 + (oc0 & 7)) = pk;
        }
    }
    if (lr == 0) {
        #pragma unroll
        for (int r = 0; r < 4; ++r)
            #pragma unroll
            for (int e = 0; e < 8; ++e)
                red[(w * 4 + lg) * 33 + r * 8 + e] = part[r][e];
    }
    __syncthreads();

    // coalesced V store
    #pragma unroll
    for (int i = 0; i < 4; ++i) {
        int e = tid + i * 256;
        int tok = e >> 4, c = e & 15;
        int cz = (c & 8) | ((c ^ tok) & 7);
        u16x8 val = *(const u16x8*)(Vt + tok * 128 + cz * 8);
        *(u16x8*)(Vbf + (tok0 + tok) * DM + c * 8) = val;
    }
    // final score partial for this block (deterministic slot per block)
    if (tid < 64) {
        int d = tid >> 3, e = tid & 7;
        int par = d >> 2, r = d & 3;
        float s = 0.f;
        #pragma unroll
        for (int ww = 0; ww < 4; ++ww)
            s += red[(ww * 4 + par) * 33 + r * 8 + e] +
                 red[(ww * 4 + par + 2) * 33 + r * 8 + e];
        scoreacc[(long)blockIdx.x * 64 + tid] = s;
    }
}

// ---------------------------------------------------------------------------
// k_medsoft: per chunk: sum 4 block-partials, *NORMF, lower-median strict
// mask, softmax -> probs[p][8][8].
// ---------------------------------------------------------------------------
__global__ __launch_bounds__(64)
void k_medsoft(const float* __restrict__ scoreacc, float* __restrict__ probs)
{
    __shared__ float sc[64], pl[64];
    const int p = blockIdx.x, tid = threadIdx.x;
    const float* s0 = scoreacc + (long)p * 256;
    sc[tid] = (s0[tid] + s0[64 + tid] + s0[128 + tid] + s0[192 + tid]) * NORMF;
    __syncthreads();
    if (tid < 8) {
        float row[8], st[8];
        #pragma unroll
        for (int e = 0; e < 8; ++e) { row[e] = sc[tid * 8 + e]; st[e] = row[e]; }
        for (int a = 1; a < 8; ++a) {
            float v = st[a]; int b = a - 1;
            while (b >= 0 && st[b] > v) { st[b + 1] = st[b]; --b; }
            st[b + 1] = v;
        }
        float med = st[3];
        float mv[8]; float mx = -3.0e38f;
        #pragma unroll
        for (int e = 0; e < 8; ++e) {
            mv[e] = (row[e] - med > 0.f) ? row[e] : -1e30f;
            mx = fmaxf(mx, mv[e]);
        }
        float z = 0.f, ex[8];
        #pragma unroll
        for (int e = 0; e < 8; ++e) { ex[e] = expf(mv[e] - mx); z += ex[e]; }
        float iz = 1.f / z;
        #pragma unroll
        for (int e = 0; e < 8; ++e) pl[tid * 8 + e] = ex[e] * iz;
    }
    __syncthreads();
    probs[(long)p * 64 + tid] = pl[tid];
}

// ---------------------------------------------------------------------------
// k_tail: fused AO-gather + Wo + LN1 + FFN + LN2 + v.  64 tok2/block.
// ---------------------------------------------------------------------------
__global__ __launch_bounds__(256, 3)
void k_tail(const ushort_t* __restrict__ Vbf, const float* __restrict__ probs,
            const ushort_t* __restrict__ Wot, const float* __restrict__ bo,
            const ushort_t* __restrict__ W1t, const float* __restrict__ b1,
            const ushort_t* __restrict__ W2t, const float* __restrict__ b2,
            const float* __restrict__ lng, const float* __restrict__ lnb,
            const float* __restrict__ vres, float* __restrict__ out)
{
    __shared__ __align__(16) char smem[51712];
    ushort_t* Xb  = (ushort_t*)smem;                 // 16 KB attn->h tile
    ushort_t* Vg  = (ushort_t*)(smem + 16384);       // 16 KB V gather
    float*    Pl  = (float*)(smem + 32768);          // 32x65 f32
    ushort_t* Hid = (ushort_t*)(smem + 16384);       // 32 KB (alias Vg+Pl)
    float* pS  = (float*)(smem + 49152);
    float* pQ  = pS + 256;
    float* muS = pQ + 256;
    float* rsS = muS + 64;

    const int tid = threadIdx.x;
    const int w = tid >> 6, l = tid & 63;
    const int lr = l & 15, lg = l >> 4;
    const long T0 = (long)blockIdx.x * 64;
    const int g  = (int)(T0 >> 13);
    const int r0 = (int)((T0 & 8191) >> 5);

    // ---- stage probs for this g's 32 chunks (stride-65 padded) ----
    #pragma unroll
    for (int i = 0; i < 8; ++i) {
        int e = tid + i * 256;
        Pl[(e >> 6) * 65 + (e & 63)] = probs[(long)g * 2048 + e];
    }
    // ---- gather the 64 V rows this tile consumes ----
    #pragma unroll
    for (int i = 0; i < 4; ++i) {
        int e = tid + i * 256;
        int ri = e >> 4, c = e & 15;
        int hb = ri >> 5, bm = (ri >> 1) & 15, rr = ri & 1;
        long t = ((long)(g * 32 + hb * 16 + bm)) * 256 + r0 + rr;
        u16x8 val = *(const u16x8*)(Vbf + t * DM + c * 8);
        int cz = (c & 8) | ((c ^ (ri >> 1)) & 7);
        *(u16x8*)(Vg + ri * 128 + cz * 8) = val;
    }

    // constants (no LDS dependency)
    bf16x8 aw[2][4];
    #pragma unroll
    for (int ot = 0; ot < 2; ++ot)
        #pragma unroll
        for (int ks = 0; ks < 4; ++ks)
            aw[ot][ks] = *(const bf16x8*)(Wot + ((long)((w * 2 + ot) * 4 + ks) * 64 + l) * 8);
    f32x4 bov[2], g4[2], bb4[2], b2v[2];
    #pragma unroll
    for (int ot = 0; ot < 2; ++ot) {
        int oc0 = w * 32 + ot * 16 + lg * 4;
        bov[ot] = *(const f32x4*)(bo + oc0);
        g4[ot]  = *(const f32x4*)(lng + oc0);
        bb4[ot] = *(const f32x4*)(lnb + oc0);
        b2v[ot] = *(const f32x4*)(b2 + oc0);
    }
    __syncthreads();

    // ---- AO: attn[ti][bm*8+d] = sum_e P[p][d][e] * Vg -> Xb (bf16 swz) ----
    #pragma unroll
    for (int i = 0; i < 4; ++i) {
        int e = tid + i * 256;
        int ti = e >> 4, bm = e & 15;
        int jj = (ti & 31) >> 1, hb = ti & 1, rr = ti >> 5;
        int ri = hb * 32 + bm * 2 + rr;
        int cz = (jj & 8) | ((jj ^ (ri >> 1)) & 7);
        u16x8 v8 = *(const u16x8*)(Vg + ri * 128 + cz * 8);
        float vf[8];
        #pragma unroll
        for (int e2 = 0; e2 < 8; ++e2) vf[e2] = b2f(v8[e2]);
        const float* pp = Pl + (hb * 16 + bm) * 65;
        u16x8 pkt;
        #pragma unroll
        for (int d = 0; d < 8; ++d) {
            float s = 0.f;
            #pragma unroll
            for (int e2 = 0; e2 < 8; ++e2) s = fmaf(pp[d * 8 + e2], vf[e2], s);
            pkt[d] = f2b(s);
        }
        *(u16x8*)(Xb + xb_off(ti, bm)) = pkt;
    }
    __syncthreads();

    // ---- Wo GEMM + LN1 (h stays in registers) ----
    float vals[4][2][4];
    float sums[4], sqs[4];
    #pragma unroll
    for (int tt = 0; tt < 4; ++tt) {
        f32x4 acc0 = (f32x4){0,0,0,0}, acc1 = (f32x4){0,0,0,0};
        int tok = tt * 16 + lr;
        #pragma unroll
        for (int ks = 0; ks < 4; ++ks) {
            bf16x8 bfrag = *(const bf16x8*)(Xb + xb_off(tok, ks * 4 + lg));
            acc0 = mfma16(aw[0][ks], bfrag, acc0);
            acc1 = mfma16(aw[1][ks], bfrag, acc1);
        }
        long gtok = T0 + tok;
        float s = 0.f, q = 0.f;
        #pragma unroll
        for (int ot = 0; ot < 2; ++ot) {
            int oc0 = w * 32 + ot * 16 + lg * 4;
            f32x4 xv = *(const f32x4*)(vres + gtok * DM + oc0);
            #pragma unroll
            for (int r = 0; r < 4; ++r) {
                float av = ot ? acc1[r] : acc0[r];
                float vvv = av + bov[ot][r] + xv[r];
                vals[tt][ot][r] = vvv;
                s += vvv; q = fmaf(vvv, vvv, q);
            }
        }
        sums[tt] = s; sqs[tt] = q;
    }
    #pragma unroll
    for (int tt = 0; tt < 4; ++tt) {
        sums[tt] += __shfl_xor(sums[tt], 16);
        sums[tt] += __shfl_xor(sums[tt], 32);
        sqs[tt]  += __shfl_xor(sqs[tt], 16);
        sqs[tt]  += __shfl_xor(sqs[tt], 32);
    }
    #pragma unroll
    for (int tt = 0; tt < 4; ++tt)
        if (lg == tt) { pS[(w * 4 + tt) * 16 + lr] = sums[tt];
                        pQ[(w * 4 + tt) * 16 + lr] = sqs[tt]; }
    __syncthreads();
    if (tid < 64) {
        float s = pS[tid] + pS[64 + tid] + pS[128 + tid] + pS[192 + tid];
        float q = pQ[tid] + pQ[64 + tid] + pQ[128 + tid] + pQ[192 + tid];
        float mu = s * 0.0078125f;
        float var = q * 0.0078125f - mu * mu;
        muS[tid] = mu;
        rsS[tid] = rsqrtf(var + 1e-5f);
    }
    __syncthreads();
    // finalize h in regs; repack bf16 h into Xb (attn reads all done)
    #pragma unroll
    for (int tt = 0; tt < 4; ++tt) {
        int tok = tt * 16 + lr;
        float mu = muS[tok], rs = rsS[tok];
        #pragma unroll
        for (int ot = 0; ot < 2; ++ot) {
            int oc0 = w * 32 + ot * 16 + lg * 4;
            float hf[4];
            #pragma unroll
            for (int r = 0; r < 4; ++r) {
                hf[r] = (vals[tt][ot][r] - mu) * rs * g4[ot][r] + bb4[ot][r];
                vals[tt][ot][r] = hf[r];
            }
            int ch = oc0 >> 3;
            int cz = (ch & 8) | ((ch ^ tok) & 7);
            u32x2 pk = {pack2(hf[0], hf[1]), pack2(hf[2], hf[3])};
            *(u32x2*)(Xb + tok * 128 + cz * 8 + (oc0 & 7)) = pk;
        }
    }
    __syncthreads();

    // ---- FFN: 2 hidden slices of 256 ----
    f32x4 oacc[4][2];
    #pragma unroll
    for (int tt = 0; tt < 4; ++tt) {
        oacc[tt][0] = (f32x4){0,0,0,0};
        oacc[tt][1] = (f32x4){0,0,0,0};
    }
    #pragma unroll
    for (int sl = 0; sl < 2; ++sl) {
        // stage 1: Hid-slice = gelu(X@W1_sl + b1_sl), transposed D
        #pragma unroll
        for (int hp = 0; hp < 2; ++hp) {
            bf16x8 a1[2][4];
            #pragma unroll
            for (int hh = 0; hh < 2; ++hh)
                #pragma unroll
                for (int ks = 0; ks < 4; ++ks)
                    a1[hh][ks] = *(const bf16x8*)(W1t +
                        ((long)((sl * 16 + w * 4 + hp * 2 + hh) * 4 + ks) * 64 + l) * 8);
            f32x4 b1v[2];
            #pragma unroll
            for (int hh = 0; hh < 2; ++hh)
                b1v[hh] = *(const f32x4*)(b1 + sl * 256 + w * 64 + (hp * 2 + hh) * 16 + lg * 4);
            #pragma unroll
            for (int tt = 0; tt < 4; ++tt) {
                f32x4 acc[2] = {(f32x4){0,0,0,0}, (f32x4){0,0,0,0}};
                int tok = tt * 16 + lr;
                #pragma unroll
                for (int ks = 0; ks < 4; ++ks) {
                    bf16x8 bfrag = *(const bf16x8*)(Xb + xb_off(tok, ks * 4 + lg));
                    acc[0] = mfma16(a1[0][ks], bfrag, acc[0]);
                    acc[1] = mfma16(a1[1][ks], bfrag, acc[1]);
                }
                #pragma unroll
                for (int hh = 0; hh < 2; ++hh) {
                    float gg[4];
                    #pragma unroll
                    for (int r = 0; r < 4; ++r)
                        gg[r] = gelu_f(acc[hh][r] + b1v[hh][r]);
                    int hc0 = w * 64 + (hp * 2 + hh) * 16 + lg * 4;
                    int ch = hc0 >> 3;
                    int cz = (ch & 24) | ((ch ^ tok) & 7);
                    u32x2 pk = {pack2(gg[0], gg[1]), pack2(gg[2], gg[3])};
                    *(u32x2*)(Hid + tok * 256 + cz * 8 + (hc0 & 7)) = pk;
                }
            }
        }
        __syncthreads();
        // stage 2: accumulate slice
        #pragma unroll
        for (int op = 0; op < 2; ++op) {
            bf16x8 a2[8];
            #pragma unroll
            for (int kl = 0; kl < 8; ++kl)
                a2[kl] = *(const bf16x8*)(W2t +
                    ((long)((w * 2 + op) * 16 + sl * 8 + kl) * 64 + l) * 8);
            #pragma unroll
            for (int tt = 0; tt < 4; ++tt) {
                int tok = tt * 16 + lr;
                #pragma unroll
                for (int kl = 0; kl < 8; ++kl) {
                    bf16x8 bfrag = *(const bf16x8*)(Hid + h2_off(tok, kl * 4 + lg));
                    oacc[tt][op] = mfma16(a2[kl], bfrag, oacc[tt][op]);
                }
            }
        }
        __syncthreads();
    }

    // ---- LN2 epilogue: out = LN(h + ffn) + v ----
    #pragma unroll
    for (int tt = 0; tt < 4; ++tt) {
        float s = 0.f, q = 0.f;
        #pragma unroll
        for (int ot = 0; ot < 2; ++ot)
            #pragma unroll
            for (int r = 0; r < 4; ++r) {
                float vvv = oacc[tt][ot][r] + b2v[ot][r] + vals[tt][ot][r];
                vals[tt][ot][r] = vvv;
                s += vvv; q = fmaf(vvv, vvv, q);
            }
        sums[tt] = s; sqs[tt] = q;
    }
    #pragma unroll
    for (int tt = 0; tt < 4; ++tt) {
        sums[tt] += __shfl_xor(sums[tt], 16);
        sums[tt] += __shfl_xor(sums[tt], 32);
        sqs[tt]  += __shfl_xor(sqs[tt], 16);
        sqs[tt]  += __shfl_xor(sqs[tt], 32);
    }
    #pragma unroll
    for (int tt = 0; tt < 4; ++tt)
        if (lg == tt) { pS[(w * 4 + tt) * 16 + lr] = sums[tt];
                        pQ[(w * 4 + tt) * 16 + lr] = sqs[tt]; }
    __syncthreads();
    if (tid < 64) {
        float s = pS[tid] + pS[64 + tid] + pS[128 + tid] + pS[192 + tid];
        float q = pQ[tid] + pQ[64 + tid] + pQ[128 + tid] + pQ[192 + tid];
        float mu = s * 0.0078125f;
        float var = q * 0.0078125f - mu * mu;
        muS[tid] = mu;
        rsS[tid] = rsqrtf(var + 1e-5f);
    }
    __syncthreads();
    #pragma unroll
    for (int tt = 0; tt < 4; ++tt) {
        int tok = tt * 16 + lr;
        long gtok = T0 + tok;
        float mu = muS[tok], rs = rsS[tok];
        #pragma unroll
        for (int ot = 0; ot < 2; ++ot) {
            int oc0 = w * 32 + ot * 16 + lg * 4;
            f32x4 vv4 = *(const f32x4*)(vres + gtok * DM + oc0);
            f32x4 o;
            #pragma unroll
            for (int r = 0; r < 4; ++r)
                o[r] = (vals[tt][ot][r] - mu) * rs * g4[ot][r] + bb4[ot][r] + vv4[r];
            *(f32x4*)(out + gtok * DM + oc0) = o;
        }
    }
}

// ---------------------------------------------------------------------------
extern "C" void kernel_launch(void* const* d_in, const int* in_sizes, int n_in,
                              void* d_out, int out_size, void* d_ws, size_t ws_size,
                              hipStream_t stream)
{
    const float* q   = (const float*)d_in[0];
    const float* v   = (const float*)d_in[1];
    const float* Wq  = (const float*)d_in[2];
    const float* bq  = (const float*)d_in[3];
    const float* Wk  = (const float*)d_in[4];
    const float* bk  = (const float*)d_in[5];
    const float* Wv  = (const float*)d_in[6];
    const float* bv  = (const float*)d_in[7];
    const float* Wo  = (const float*)d_in[8];
    const float* bo  = (const float*)d_in[9];
    const float* lng = (const float*)d_in[10];
    const float* lnb = (const float*)d_in[11];
    const float* W1  = (const float*)d_in[12];
    const float* b1  = (const float*)d_in[13];
    const float* W2  = (const float*)d_in[14];
    const float* b2  = (const float*)d_in[15];
    float* out = (float*)d_out;

    char* W = (char*)d_ws;
    ushort_t* Vbf      = (ushort_t*)(W);               // 32 MB
    float*    scoreacc = (float*)(W + 33554432);       // 512 KB
    float*    probs    = (float*)(W + 34078720);       // 128 KB
    char* wbase = W + 34209792;
    ushort_t* Wqh = (ushort_t*)(wbase);
    ushort_t* Wql = (ushort_t*)(wbase + 32768);
    ushort_t* Wkh = (ushort_t*)(wbase + 65536);
    ushort_t* Wkl = (ushort_t*)(wbase + 98304);
    ushort_t* Wvh = (ushort_t*)(wbase + 131072);
    ushort_t* Wvl = (ushort_t*)(wbase + 163840);
    ushort_t* W1t = (ushort_t*)(wbase + 196608);       // 128 KB
    ushort_t* W2t = (ushort_t*)(wbase + 327680);       // 128 KB
    ushort_t* Wot = (ushort_t*)(wbase + 458752);       // 32 KB

    dim3 blk(256);
    k_wcvt<<<96, blk, 0, stream>>>(W1, W2, Wo, Wq, Wk, Wv,
                                   W1t, W2t, Wot, Wqh, Wql, Wkh, Wkl, Wvh, Wvl);
    k_qkvs<<<2048, blk, 0, stream>>>(q, v, Wqh, Wql, Wkh, Wkl, Wvh, Wvl,
                                     bq, bk, bv, Vbf, scoreacc);
    k_medsoft<<<512, dim3(64), 0, stream>>>(scoreacc, probs);
    k_tail<<<2048, blk, 0, stream>>>(Vbf, probs, Wot, bo, W1t, b1, W2t, b2,
                                     lng, lnb, v, out);
}

// Round 5
// 200.809 us; speedup vs baseline: 1.3928x; 1.3928x over previous
//
#include <hip/hip_runtime.h>
#include <math.h>

// ============================================================================
// Cross-covariance transformer block.  Round 5:
//  - k_qkvs   : fused QKV (split-bf16 MFMA) + group-norm + partial scores
//  - k_medsoft: median mask + softmax -> probs
//  - k_tail   : FUSED AO-gather + Wo GEMM + LN1 + FFN + LN2 (+v).
//    Round-5 fix: launch_bounds(256,2) (was (256,3): unified VGPR+AGPR file
//    split 84/84 -> ~340 MB scratch spill, WRITE_SIZE 403 MB) and h-residual
//    re-read from LDS (bf16) so no 32-reg vals array lives across the FFN.
// ============================================================================

typedef __bf16 bf16x8 __attribute__((ext_vector_type(8)));
typedef float f32x4 __attribute__((ext_vector_type(4)));
typedef unsigned short u16x8 __attribute__((ext_vector_type(8)));
typedef unsigned int u32x2 __attribute__((ext_vector_type(2)));
typedef unsigned short ushort_t;

static constexpr int  DM   = 128;
static constexpr long NTOK = 131072;                 // B*S = 32*4096
static constexpr float NORMF = 0.17677669529663687f; // 1/sqrt(32)

__device__ __forceinline__ unsigned short f2b(float x) {
    unsigned u = __builtin_bit_cast(unsigned, x);
    return (unsigned short)((u + 0x7fffu + ((u >> 16) & 1u)) >> 16);  // RNE
}
__device__ __forceinline__ float b2f(unsigned short h) {
    return __builtin_bit_cast(float, ((unsigned)h) << 16);
}
__device__ __forceinline__ float b2f_lo(unsigned u) {
    return __builtin_bit_cast(float, u << 16);
}
__device__ __forceinline__ float b2f_hi(unsigned u) {
    return __builtin_bit_cast(float, u & 0xffff0000u);
}
__device__ __forceinline__ unsigned pack2(float a, float b) {
    return (unsigned)f2b(a) | ((unsigned)f2b(b) << 16);
}
__device__ __forceinline__ f32x4 mfma16(bf16x8 a, bf16x8 b, f32x4 c) {
    return __builtin_amdgcn_mfma_f32_16x16x32_bf16(a, b, c, 0, 0, 0);
}
// [64][128] bf16 tile, 16B chunks XOR-swizzled by tok&7
__device__ __forceinline__ int xb_off(int tok, int chunk) {
    int c = (chunk & 8) | ((chunk ^ tok) & 7);
    return tok * 128 + c * 8;
}
// [64][256] bf16 tile
__device__ __forceinline__ int h2_off(int tok, int chunk) {
    int c = (chunk & 24) | ((chunk ^ tok) & 7);
    return tok * 256 + c * 8;
}
// gelu via A&S 7.1.26 erf approx (|err| ~1.5e-7)
__device__ __forceinline__ float gelu_f(float x) {
    float t = 0.70710678118654752f * x;
    float s = fabsf(t);
    float u = __builtin_amdgcn_rcpf(fmaf(0.3275911f, s, 1.0f));
    float p = fmaf(fmaf(fmaf(fmaf(1.061405429f, u, -1.453152027f), u,
                             1.421413741f), u, -0.284496736f), u, 0.254829592f);
    p *= u;
    float e = __expf(-s * s);
    float er = fmaf(-p, e, 1.0f);
    er = (t < 0.f) ? -er : er;
    return 0.5f * x * (1.0f + er);
}

// ---------------------------------------------------------------------------
// k_wcvt: weights -> MFMA-A-fragment-linear bf16 (W1/W2/Wo single, Wq/Wk/Wv
// hi/lo split).  A-frag: value = W[k][m], m = ot*16+lr, k = ks*32+lg*8+j.
// ---------------------------------------------------------------------------
__global__ __launch_bounds__(256)
void k_wcvt(const float* __restrict__ W1, const float* __restrict__ W2,
            const float* __restrict__ Wo, const float* __restrict__ Wq,
            const float* __restrict__ Wk, const float* __restrict__ Wv,
            ushort_t* __restrict__ W1t, ushort_t* __restrict__ W2t,
            ushort_t* __restrict__ Wot,
            ushort_t* __restrict__ Wqh, ushort_t* __restrict__ Wql,
            ushort_t* __restrict__ Wkh, ushort_t* __restrict__ Wkl,
            ushort_t* __restrict__ Wvh, ushort_t* __restrict__ Wvl)
{
    int frag = blockIdx.x * 4 + (threadIdx.x >> 6);
    int l = threadIdx.x & 63;
    int lr = l & 15, lg = l >> 4;
    u16x8 v;
    if (frag < 128) {                       // W1t: 32 hcol-tiles x 4 k-steps
        int ht = frag >> 2, ks = frag & 3;
        #pragma unroll
        for (int j = 0; j < 8; ++j)
            v[j] = f2b(W1[(ks * 32 + lg * 8 + j) * 512 + ht * 16 + lr]);
        *(u16x8*)(W1t + ((long)frag * 64 + l) * 8) = v;
    } else if (frag < 256) {                // W2t: 8 oc-tiles x 16 k-steps
        int f = frag - 128;
        int ot = f >> 4, ks = f & 15;
        #pragma unroll
        for (int j = 0; j < 8; ++j)
            v[j] = f2b(W2[(ks * 32 + lg * 8 + j) * 128 + ot * 16 + lr]);
        *(u16x8*)(W2t + ((long)f * 64 + l) * 8) = v;
    } else if (frag < 288) {                // Wot: 8 oc-tiles x 4 k-steps
        int f = frag - 256;
        int ot = f >> 2, ks = f & 3;
        #pragma unroll
        for (int j = 0; j < 8; ++j)
            v[j] = f2b(Wo[(ks * 32 + lg * 8 + j) * 128 + ot * 16 + lr]);
        *(u16x8*)(Wot + ((long)f * 64 + l) * 8) = v;
    } else {                                // Wq/Wk/Wv hi+lo, 32 frags each
        int f = frag - 288;
        const float* S = (f < 32) ? Wq : (f < 64) ? Wk : Wv;
        ushort_t* dh = (f < 32) ? Wqh : (f < 64) ? Wkh : Wvh;
        ushort_t* dl = (f < 32) ? Wql : (f < 64) ? Wkl : Wvl;
        int fl = f & 31, ot = fl >> 2, ks = fl & 3;
        u16x8 vh, vl;
        #pragma unroll
        for (int j = 0; j < 8; ++j) {
            float x = S[(ks * 32 + lg * 8 + j) * 128 + ot * 16 + lr];
            unsigned short h = f2b(x);
            vh[j] = h;
            vl[j] = f2b(x - b2f(h));
        }
        *(u16x8*)(dh + ((long)fl * 64 + l) * 8) = vh;
        *(u16x8*)(dl + ((long)fl * 64 + l) * 8) = vl;
    }
}

// ---------------------------------------------------------------------------
// k_qkvs: 64 tokens/block.  Split-bf16 MFMA for Q (from v), K,V (from q);
// 8-group normalize Q,K; partial scores -> scoreacc[block][64];
// V (bf16) -> global via LDS transpose.
// ---------------------------------------------------------------------------
__global__ __launch_bounds__(256, 2)
void k_qkvs(const float* __restrict__ qin, const float* __restrict__ vin,
            const ushort_t* __restrict__ Wqh, const ushort_t* __restrict__ Wql,
            const ushort_t* __restrict__ Wkh, const ushort_t* __restrict__ Wkl,
            const ushort_t* __restrict__ Wvh, const ushort_t* __restrict__ Wvl,
            const float* __restrict__ bq, const float* __restrict__ bk,
            const float* __restrict__ bv,
            ushort_t* __restrict__ Vbf, float* __restrict__ scoreacc)
{
    __shared__ __align__(16) char smem[65536];
    ushort_t* vhi = (ushort_t*)smem;            // [64][128] swz  (input v)
    ushort_t* vlo = vhi + 8192;
    ushort_t* qhi = vlo + 8192;                 // (input q)
    ushort_t* qlo = qhi + 8192;
    ushort_t* Vt  = (ushort_t*)smem;            // alias (16 KB) after phases
    float*    red = (float*)(smem + 16384);     // [16][33] alias

    const int tid = threadIdx.x;
    const int w = tid >> 6, l = tid & 63;
    const int lr = l & 15, lg = l >> 4;
    const long tok0 = (long)blockIdx.x * 64;

    // ---- stage inputs, split hi/lo ----
    #pragma unroll
    for (int i = 0; i < 4; ++i) {
        int e = tid + i * 256;
        int tok = e >> 4, c = e & 15;
        long base = (tok0 + tok) * DM + c * 8;
        int xo = xb_off(tok, c);
        {
            float4 a0 = *(const float4*)(vin + base);
            float4 a1 = *(const float4*)(vin + base + 4);
            float xs[8] = {a0.x, a0.y, a0.z, a0.w, a1.x, a1.y, a1.z, a1.w};
            u16x8 hi, lo;
            #pragma unroll
            for (int jj = 0; jj < 8; ++jj) {
                unsigned short h = f2b(xs[jj]);
                hi[jj] = h; lo[jj] = f2b(xs[jj] - b2f(h));
            }
            *(u16x8*)(vhi + xo) = hi;
            *(u16x8*)(vlo + xo) = lo;
        }
        {
            float4 a0 = *(const float4*)(qin + base);
            float4 a1 = *(const float4*)(qin + base + 4);
            float xs[8] = {a0.x, a0.y, a0.z, a0.w, a1.x, a1.y, a1.z, a1.w};
            u16x8 hi, lo;
            #pragma unroll
            for (int jj = 0; jj < 8; ++jj) {
                unsigned short h = f2b(xs[jj]);
                hi[jj] = h; lo[jj] = f2b(xs[jj] - b2f(h));
            }
            *(u16x8*)(qhi + xo) = hi;
            *(u16x8*)(qlo + xo) = lo;
        }
    }
    __syncthreads();

    // ---- Q phase (input v) ----
    float qv[2][4][4];
    {
        f32x4 acc[2][4];
        #pragma unroll
        for (int ot = 0; ot < 2; ++ot)
            #pragma unroll
            for (int tt = 0; tt < 4; ++tt) acc[ot][tt] = (f32x4){0,0,0,0};
        #pragma unroll
        for (int ks = 0; ks < 4; ++ks) {
            bf16x8 wh[2], wl[2];
            #pragma unroll
            for (int ot = 0; ot < 2; ++ot) {
                int fi = (((w * 2 + ot) * 4 + ks) * 64 + l) * 8;
                wh[ot] = *(const bf16x8*)(Wqh + fi);
                wl[ot] = *(const bf16x8*)(Wql + fi);
            }
            #pragma unroll
            for (int tt = 0; tt < 4; ++tt) {
                int xo = xb_off(tt * 16 + lr, ks * 4 + lg);
                bf16x8 xh = *(const bf16x8*)(vhi + xo);
                bf16x8 xl = *(const bf16x8*)(vlo + xo);
                #pragma unroll
                for (int ot = 0; ot < 2; ++ot) {
                    acc[ot][tt] = mfma16(wh[ot], xh, acc[ot][tt]);
                    acc[ot][tt] = mfma16(wh[ot], xl, acc[ot][tt]);
                    acc[ot][tt] = mfma16(wl[ot], xh, acc[ot][tt]);
                }
            }
        }
        #pragma unroll
        for (int ot = 0; ot < 2; ++ot) {
            f32x4 bqv = *(const f32x4*)(bq + w * 32 + ot * 16 + lg * 4);
            #pragma unroll
            for (int tt = 0; tt < 4; ++tt) {
                float s2 = 0.f;
                #pragma unroll
                for (int r = 0; r < 4; ++r) {
                    float x = acc[ot][tt][r] + bqv[r];
                    qv[ot][tt][r] = x;
                    s2 = fmaf(x, x, s2);
                }
                s2 += __shfl_xor(s2, 16);
                float inv = 1.0f / fmaxf(sqrtf(s2), 1e-12f);
                #pragma unroll
                for (int r = 0; r < 4; ++r) qv[ot][tt][r] *= inv;
            }
        }
    }

    // ---- K+V phase (input q) + incremental score accumulation ----
    float vv[2][4][4];
    float part[4][8];
    #pragma unroll
    for (int r = 0; r < 4; ++r)
        #pragma unroll
        for (int e = 0; e < 8; ++e) part[r][e] = 0.f;
    {
        f32x4 acck[2][4], accv[2][4];
        #pragma unroll
        for (int ot = 0; ot < 2; ++ot)
            #pragma unroll
            for (int tt = 0; tt < 4; ++tt) {
                acck[ot][tt] = (f32x4){0,0,0,0};
                accv[ot][tt] = (f32x4){0,0,0,0};
            }
        #pragma unroll
        for (int ks = 0; ks < 4; ++ks) {
            bf16x8 whk[2], wlk[2], whv[2], wlv[2];
            #pragma unroll
            for (int ot = 0; ot < 2; ++ot) {
                int fi = (((w * 2 + ot) * 4 + ks) * 64 + l) * 8;
                whk[ot] = *(const bf16x8*)(Wkh + fi);
                wlk[ot] = *(const bf16x8*)(Wkl + fi);
                whv[ot] = *(const bf16x8*)(Wvh + fi);
                wlv[ot] = *(const bf16x8*)(Wvl + fi);
            }
            #pragma unroll
            for (int tt = 0; tt < 4; ++tt) {
                int xo = xb_off(tt * 16 + lr, ks * 4 + lg);
                bf16x8 xh = *(const bf16x8*)(qhi + xo);
                bf16x8 xl = *(const bf16x8*)(qlo + xo);
                #pragma unroll
                for (int ot = 0; ot < 2; ++ot) {
                    acck[ot][tt] = mfma16(whk[ot], xh, acck[ot][tt]);
                    acck[ot][tt] = mfma16(whk[ot], xl, acck[ot][tt]);
                    acck[ot][tt] = mfma16(wlk[ot], xh, acck[ot][tt]);
                    accv[ot][tt] = mfma16(whv[ot], xh, accv[ot][tt]);
                    accv[ot][tt] = mfma16(whv[ot], xl, accv[ot][tt]);
                    accv[ot][tt] = mfma16(wlv[ot], xh, accv[ot][tt]);
                }
            }
        }
        const int h0 = (lg & 1) * 4;
        #pragma unroll
        for (int ot = 0; ot < 2; ++ot) {
            f32x4 bkv = *(const f32x4*)(bk + w * 32 + ot * 16 + lg * 4);
            f32x4 bvv = *(const f32x4*)(bv + w * 32 + ot * 16 + lg * 4);
            #pragma unroll
            for (int tt = 0; tt < 4; ++tt) {
                float kq[4];
                float s2 = 0.f;
                #pragma unroll
                for (int r = 0; r < 4; ++r) {
                    float x = acck[ot][tt][r] + bkv[r];
                    kq[r] = x;
                    s2 = fmaf(x, x, s2);
                    vv[ot][tt][r] = accv[ot][tt][r] + bvv[r];
                }
                s2 += __shfl_xor(s2, 16);
                float inv = 1.0f / fmaxf(sqrtf(s2), 1e-12f);
                #pragma unroll
                for (int r = 0; r < 4; ++r) kq[r] *= inv;
                float ko[4];
                #pragma unroll
                for (int r = 0; r < 4; ++r) ko[r] = __shfl_xor(kq[r], 16);
                float ke[8];
                #pragma unroll
                for (int r = 0; r < 4; ++r) {
                    ke[h0 + r] = kq[r];
                    ke[(h0 ^ 4) + r] = ko[r];
                }
                #pragma unroll
                for (int r = 0; r < 4; ++r)
                    #pragma unroll
                    for (int e = 0; e < 8; ++e)
                        part[r][e] = fmaf(qv[ot][tt][r], ke[e], part[r][e]);
            }
        }
    }
    // reduce partials over lr lanes (bits 0..3)
    #pragma unroll
    for (int r = 0; r < 4; ++r)
        #pragma unroll
        for (int e = 0; e < 8; ++e) {
            float p = part[r][e];
            p += __shfl_xor(p, 1);
            p += __shfl_xor(p, 2);
            p += __shfl_xor(p, 4);
            p += __shfl_xor(p, 8);
            part[r][e] = p;
        }
    __syncthreads();   // x-tiles fully consumed; alias regions now writable

    // V regs -> Vt (swizzled bf16 [64][128])
    #pragma unroll
    for (int ot = 0; ot < 2; ++ot) {
        int oc0 = w * 32 + ot * 16 + lg * 4;
        int ch = oc0 >> 3;
        #pragma unroll
        for (int tt = 0; tt < 4; ++tt) {
            int tok = tt * 16 + lr;
            int cz = (ch & 8) | ((ch ^ tok) & 7);
            u32x2 pk = {pack2(vv[ot][tt][0], vv[ot][tt][1]),
                        pack2(vv[ot][tt][2], vv[ot][tt][3])};
            *(u32x2*)(Vt + tok * 128 + cz * 8 + (oc0 & 7)) = pk;
        }
    }
    if (lr == 0) {
        #pragma unroll
        for (int r = 0; r < 4; ++r)
            #pragma unroll
            for (int e = 0; e < 8; ++e)
                red[(w * 4 + lg) * 33 + r * 8 + e] = part[r][e];
    }
    __syncthreads();

    // coalesced V store
    #pragma unroll
    for (int i = 0; i < 4; ++i) {
        int e = tid + i * 256;
        int tok = e >> 4, c = e & 15;
        int cz = (c & 8) | ((c ^ tok) & 7);
        u16x8 val = *(const u16x8*)(Vt + tok * 128 + cz * 8);
        *(u16x8*)(Vbf + (tok0 + tok) * DM + c * 8) = val;
    }
    // final score partial for this block (deterministic slot per block)
    if (tid < 64) {
        int d = tid >> 3, e = tid & 7;
        int par = d >> 2, r = d & 3;
        float s = 0.f;
        #pragma unroll
        for (int ww = 0; ww < 4; ++ww)
            s += red[(ww * 4 + par) * 33 + r * 8 + e] +
                 red[(ww * 4 + par + 2) * 33 + r * 8 + e];
        scoreacc[(long)blockIdx.x * 64 + tid] = s;
    }
}

// ---------------------------------------------------------------------------
// k_medsoft: per chunk: sum 4 block-partials, *NORMF, lower-median strict
// mask, softmax -> probs[p][8][8].
// ---------------------------------------------------------------------------
__global__ __launch_bounds__(64)
void k_medsoft(const float* __restrict__ scoreacc, float* __restrict__ probs)
{
    __shared__ float sc[64], pl[64];
    const int p = blockIdx.x, tid = threadIdx.x;
    const float* s0 = scoreacc + (long)p * 256;
    sc[tid] = (s0[tid] + s0[64 + tid] + s0[128 + tid] + s0[192 + tid]) * NORMF;
    __syncthreads();
    if (tid < 8) {
        float row[8], st[8];
        #pragma unroll
        for (int e = 0; e < 8; ++e) { row[e] = sc[tid * 8 + e]; st[e] = row[e]; }
        for (int a = 1; a < 8; ++a) {
            float v = st[a]; int b = a - 1;
            while (b >= 0 && st[b] > v) { st[b + 1] = st[b]; --b; }
            st[b + 1] = v;
        }
        float med = st[3];
        float mv[8]; float mx = -3.0e38f;
        #pragma unroll
        for (int e = 0; e < 8; ++e) {
            mv[e] = (row[e] - med > 0.f) ? row[e] : -1e30f;
            mx = fmaxf(mx, mv[e]);
        }
        float z = 0.f, ex[8];
        #pragma unroll
        for (int e = 0; e < 8; ++e) { ex[e] = expf(mv[e] - mx); z += ex[e]; }
        float iz = 1.f / z;
        #pragma unroll
        for (int e = 0; e < 8; ++e) pl[tid * 8 + e] = ex[e] * iz;
    }
    __syncthreads();
    probs[(long)p * 64 + tid] = pl[tid];
}

// ---------------------------------------------------------------------------
// k_tail: fused AO-gather + Wo + LN1 + FFN + LN2 + v.  64 tok2/block.
// ---------------------------------------------------------------------------
__global__ __launch_bounds__(256, 2)
void k_tail(const ushort_t* __restrict__ Vbf, const float* __restrict__ probs,
            const ushort_t* __restrict__ Wot, const float* __restrict__ bo,
            const ushort_t* __restrict__ W1t, const float* __restrict__ b1,
            const ushort_t* __restrict__ W2t, const float* __restrict__ b2,
            const float* __restrict__ lng, const float* __restrict__ lnb,
            const float* __restrict__ vres, float* __restrict__ out)
{
    __shared__ __align__(16) char smem[51712];
    ushort_t* Xb  = (ushort_t*)smem;                 // 16 KB attn->h tile
    ushort_t* Vg  = (ushort_t*)(smem + 16384);       // 16 KB V gather
    float*    Pl  = (float*)(smem + 32768);          // 32x65 f32
    ushort_t* Hid = (ushort_t*)(smem + 16384);       // 32 KB (alias Vg+Pl)
    float* pS  = (float*)(smem + 49152);
    float* pQ  = pS + 256;
    float* muS = pQ + 256;
    float* rsS = muS + 64;

    const int tid = threadIdx.x;
    const int w = tid >> 6, l = tid & 63;
    const int lr = l & 15, lg = l >> 4;
    const long T0 = (long)blockIdx.x * 64;
    const int g  = (int)(T0 >> 13);
    const int r0 = (int)((T0 & 8191) >> 5);

    // ---- stage probs for this g's 32 chunks (stride-65 padded) ----
    #pragma unroll
    for (int i = 0; i < 8; ++i) {
        int e = tid + i * 256;
        Pl[(e >> 6) * 65 + (e & 63)] = probs[(long)g * 2048 + e];
    }
    // ---- gather the 64 V rows this tile consumes ----
    #pragma unroll
    for (int i = 0; i < 4; ++i) {
        int e = tid + i * 256;
        int ri = e >> 4, c = e & 15;
        int hb = ri >> 5, bm = (ri >> 1) & 15, rr = ri & 1;
        long t = ((long)(g * 32 + hb * 16 + bm)) * 256 + r0 + rr;
        u16x8 val = *(const u16x8*)(Vbf + t * DM + c * 8);
        int cz = (c & 8) | ((c ^ (ri >> 1)) & 7);
        *(u16x8*)(Vg + ri * 128 + cz * 8) = val;
    }

    // constants (no LDS dependency)
    bf16x8 aw[2][4];
    #pragma unroll
    for (int ot = 0; ot < 2; ++ot)
        #pragma unroll
        for (int ks = 0; ks < 4; ++ks)
            aw[ot][ks] = *(const bf16x8*)(Wot + ((long)((w * 2 + ot) * 4 + ks) * 64 + l) * 8);
    f32x4 bov[2], g4[2], bb4[2], b2v[2];
    #pragma unroll
    for (int ot = 0; ot < 2; ++ot) {
        int oc0 = w * 32 + ot * 16 + lg * 4;
        bov[ot] = *(const f32x4*)(bo + oc0);
        g4[ot]  = *(const f32x4*)(lng + oc0);
        bb4[ot] = *(const f32x4*)(lnb + oc0);
        b2v[ot] = *(const f32x4*)(b2 + oc0);
    }
    __syncthreads();

    // ---- AO: attn[ti][bm*8+d] = sum_e P[p][d][e] * Vg -> Xb (bf16 swz) ----
    #pragma unroll
    for (int i = 0; i < 4; ++i) {
        int e = tid + i * 256;
        int ti = e >> 4, bm = e & 15;
        int jj = (ti & 31) >> 1, hb = ti & 1, rr = ti >> 5;
        int ri = hb * 32 + bm * 2 + rr;
        int cz = (jj & 8) | ((jj ^ (ri >> 1)) & 7);
        u16x8 v8 = *(const u16x8*)(Vg + ri * 128 + cz * 8);
        float vf[8];
        #pragma unroll
        for (int e2 = 0; e2 < 8; ++e2) vf[e2] = b2f(v8[e2]);
        const float* pp = Pl + (hb * 16 + bm) * 65;
        u16x8 pkt;
        #pragma unroll
        for (int d = 0; d < 8; ++d) {
            float s = 0.f;
            #pragma unroll
            for (int e2 = 0; e2 < 8; ++e2) s = fmaf(pp[d * 8 + e2], vf[e2], s);
            pkt[d] = f2b(s);
        }
        *(u16x8*)(Xb + xb_off(ti, bm)) = pkt;
    }
    __syncthreads();

    // ---- Wo GEMM + LN1 (h transient in registers, then -> Xb as bf16) ----
    float vals[4][2][4];
    float sums[4], sqs[4];
    #pragma unroll
    for (int tt = 0; tt < 4; ++tt) {
        f32x4 acc0 = (f32x4){0,0,0,0}, acc1 = (f32x4){0,0,0,0};
        int tok = tt * 16 + lr;
        #pragma unroll
        for (int ks = 0; ks < 4; ++ks) {
            bf16x8 bfrag = *(const bf16x8*)(Xb + xb_off(tok, ks * 4 + lg));
            acc0 = mfma16(aw[0][ks], bfrag, acc0);
            acc1 = mfma16(aw[1][ks], bfrag, acc1);
        }
        long gtok = T0 + tok;
        float s = 0.f, q = 0.f;
        #pragma unroll
        for (int ot = 0; ot < 2; ++ot) {
            int oc0 = w * 32 + ot * 16 + lg * 4;
            f32x4 xv = *(const f32x4*)(vres + gtok * DM + oc0);
            #pragma unroll
            for (int r = 0; r < 4; ++r) {
                float av = ot ? acc1[r] : acc0[r];
                float vvv = av + bov[ot][r] + xv[r];
                vals[tt][ot][r] = vvv;
                s += vvv; q = fmaf(vvv, vvv, q);
            }
        }
        sums[tt] = s; sqs[tt] = q;
    }
    #pragma unroll
    for (int tt = 0; tt < 4; ++tt) {
        sums[tt] += __shfl_xor(sums[tt], 16);
        sums[tt] += __shfl_xor(sums[tt], 32);
        sqs[tt]  += __shfl_xor(sqs[tt], 16);
        sqs[tt]  += __shfl_xor(sqs[tt], 32);
    }
    #pragma unroll
    for (int tt = 0; tt < 4; ++tt)
        if (lg == tt) { pS[(w * 4 + tt) * 16 + lr] = sums[tt];
                        pQ[(w * 4 + tt) * 16 + lr] = sqs[tt]; }
    __syncthreads();
    if (tid < 64) {
        float s = pS[tid] + pS[64 + tid] + pS[128 + tid] + pS[192 + tid];
        float q = pQ[tid] + pQ[64 + tid] + pQ[128 + tid] + pQ[192 + tid];
        float mu = s * 0.0078125f;
        float var = q * 0.0078125f - mu * mu;
        muS[tid] = mu;
        rsS[tid] = rsqrtf(var + 1e-5f);
    }
    __syncthreads();
    // finalize h -> Xb as bf16 (vals dead after this; FFN + LN2 read Xb)
    #pragma unroll
    for (int tt = 0; tt < 4; ++tt) {
        int tok = tt * 16 + lr;
        float mu = muS[tok], rs = rsS[tok];
        #pragma unroll
        for (int ot = 0; ot < 2; ++ot) {
            int oc0 = w * 32 + ot * 16 + lg * 4;
            float hf[4];
            #pragma unroll
            for (int r = 0; r < 4; ++r)
                hf[r] = (vals[tt][ot][r] - mu) * rs * g4[ot][r] + bb4[ot][r];
            int ch = oc0 >> 3;
            int cz = (ch & 8) | ((ch ^ tok) & 7);
            u32x2 pk = {pack2(hf[0], hf[1]), pack2(hf[2], hf[3])};
            *(u32x2*)(Xb + tok * 128 + cz * 8 + (oc0 & 7)) = pk;
        }
    }
    __syncthreads();

    // ---- FFN: 2 hidden slices of 256 ----
    f32x4 oacc[4][2];
    #pragma unroll
    for (int tt = 0; tt < 4; ++tt) {
        oacc[tt][0] = (f32x4){0,0,0,0};
        oacc[tt][1] = (f32x4){0,0,0,0};
    }
    #pragma unroll
    for (int sl = 0; sl < 2; ++sl) {
        // stage 1: Hid-slice = gelu(X@W1_sl + b1_sl), transposed D
        #pragma unroll
        for (int hp = 0; hp < 2; ++hp) {
            bf16x8 a1[2][4];
            #pragma unroll
            for (int hh = 0; hh < 2; ++hh)
                #pragma unroll
                for (int ks = 0; ks < 4; ++ks)
                    a1[hh][ks] = *(const bf16x8*)(W1t +
                        ((long)((sl * 16 + w * 4 + hp * 2 + hh) * 4 + ks) * 64 + l) * 8);
            f32x4 b1v[2];
            #pragma unroll
            for (int hh = 0; hh < 2; ++hh)
                b1v[hh] = *(const f32x4*)(b1 + sl * 256 + w * 64 + (hp * 2 + hh) * 16 + lg * 4);
            #pragma unroll
            for (int tt = 0; tt < 4; ++tt) {
                f32x4 acc[2] = {(f32x4){0,0,0,0}, (f32x4){0,0,0,0}};
                int tok = tt * 16 + lr;
                #pragma unroll
                for (int ks = 0; ks < 4; ++ks) {
                    bf16x8 bfrag = *(const bf16x8*)(Xb + xb_off(tok, ks * 4 + lg));
                    acc[0] = mfma16(a1[0][ks], bfrag, acc[0]);
                    acc[1] = mfma16(a1[1][ks], bfrag, acc[1]);
                }
                #pragma unroll
                for (int hh = 0; hh < 2; ++hh) {
                    float gg[4];
                    #pragma unroll
                    for (int r = 0; r < 4; ++r)
                        gg[r] = gelu_f(acc[hh][r] + b1v[hh][r]);
                    int hc0 = w * 64 + (hp * 2 + hh) * 16 + lg * 4;
                    int ch = hc0 >> 3;
                    int cz = (ch & 24) | ((ch ^ tok) & 7);
                    u32x2 pk = {pack2(gg[0], gg[1]), pack2(gg[2], gg[3])};
                    *(u32x2*)(Hid + tok * 256 + cz * 8 + (hc0 & 7)) = pk;
                }
            }
        }
        __syncthreads();
        // stage 2: accumulate slice
        #pragma unroll
        for (int op = 0; op < 2; ++op) {
            bf16x8 a2[8];
            #pragma unroll
            for (int kl = 0; kl < 8; ++kl)
                a2[kl] = *(const bf16x8*)(W2t +
                    ((long)((w * 2 + op) * 16 + sl * 8 + kl) * 64 + l) * 8);
            #pragma unroll
            for (int tt = 0; tt < 4; ++tt) {
                int tok = tt * 16 + lr;
                #pragma unroll
                for (int kl = 0; kl < 8; ++kl) {
                    bf16x8 bfrag = *(const bf16x8*)(Hid + h2_off(tok, kl * 4 + lg));
                    oacc[tt][op] = mfma16(a2[kl], bfrag, oacc[tt][op]);
                }
            }
        }
        __syncthreads();
    }

    // ---- LN2 epilogue: out = LN(h + ffn) + v, h re-read from Xb (bf16) ----
    #pragma unroll
    for (int tt = 0; tt < 4; ++tt) {
        int tok = tt * 16 + lr;
        float s = 0.f, q = 0.f;
        #pragma unroll
        for (int ot = 0; ot < 2; ++ot) {
            int oc0 = w * 32 + ot * 16 + lg * 4;
            int ch = oc0 >> 3;
            int cz = (ch & 8) | ((ch ^ tok) & 7);
            u32x2 hp = *(const u32x2*)(Xb + tok * 128 + cz * 8 + (oc0 & 7));
            float hr[4] = {b2f_lo(hp[0]), b2f_hi(hp[0]),
                           b2f_lo(hp[1]), b2f_hi(hp[1])};
            #pragma unroll
            for (int r = 0; r < 4; ++r) {
                float vvv = oacc[tt][ot][r] + b2v[ot][r] + hr[r];
                s += vvv; q = fmaf(vvv, vvv, q);
            }
        }
        sums[tt] = s; sqs[tt] = q;
    }
    #pragma unroll
    for (int tt = 0; tt < 4; ++tt) {
        sums[tt] += __shfl_xor(sums[tt], 16);
        sums[tt] += __shfl_xor(sums[tt], 32);
        sqs[tt]  += __shfl_xor(sqs[tt], 16);
        sqs[tt]  += __shfl_xor(sqs[tt], 32);
    }
    #pragma unroll
    for (int tt = 0; tt < 4; ++tt)
        if (lg == tt) { pS[(w * 4 + tt) * 16 + lr] = sums[tt];
                        pQ[(w * 4 + tt) * 16 + lr] = sqs[tt]; }
    __syncthreads();
    if (tid < 64) {
        float s = pS[tid] + pS[64 + tid] + pS[128 + tid] + pS[192 + tid];
        float q = pQ[tid] + pQ[64 + tid] + pQ[128 + tid] + pQ[192 + tid];
        float mu = s * 0.0078125f;
        float var = q * 0.0078125f - mu * mu;
        muS[tid] = mu;
        rsS[tid] = rsqrtf(var + 1e-5f);
    }
    __syncthreads();
    #pragma unroll
    for (int tt = 0; tt < 4; ++tt) {
        int tok = tt * 16 + lr;
        long gtok = T0 + tok;
        float mu = muS[tok], rs = rsS[tok];
        #pragma unroll
        for (int ot = 0; ot < 2; ++ot) {
            int oc0 = w * 32 + ot * 16 + lg * 4;
            int ch = oc0 >> 3;
            int cz = (ch & 8) | ((ch ^ tok) & 7);
            u32x2 hp = *(const u32x2*)(Xb + tok * 128 + cz * 8 + (oc0 & 7));
            float hr[4] = {b2f_lo(hp[0]), b2f_hi(hp[0]),
                           b2f_lo(hp[1]), b2f_hi(hp[1])};
            f32x4 vv4 = *(const f32x4*)(vres + gtok * DM + oc0);
            f32x4 o;
            #pragma unroll
            for (int r = 0; r < 4; ++r) {
                float vvv = oacc[tt][ot][r] + b2v[ot][r] + hr[r];
                o[r] = (vvv - mu) * rs * g4[ot][r] + bb4[ot][r] + vv4[r];
            }
            *(f32x4*)(out + gtok * DM + oc0) = o;
        }
    }
}

// ---------------------------------------------------------------------------
extern "C" void kernel_launch(void* const* d_in, const int* in_sizes, int n_in,
                              void* d_out, int out_size, void* d_ws, size_t ws_size,
                              hipStream_t stream)
{
    const float* q   = (const float*)d_in[0];
    const float* v   = (const float*)d_in[1];
    const float* Wq  = (const float*)d_in[2];
    const float* bq  = (const float*)d_in[3];
    const float* Wk  = (const float*)d_in[4];
    const float* bk  = (const float*)d_in[5];
    const float* Wv  = (const float*)d_in[6];
    const float* bv  = (const float*)d_in[7];
    const float* Wo  = (const float*)d_in[8];
    const float* bo  = (const float*)d_in[9];
    const float* lng = (const float*)d_in[10];
    const float* lnb = (const float*)d_in[11];
    const float* W1  = (const float*)d_in[12];
    const float* b1  = (const float*)d_in[13];
    const float* W2  = (const float*)d_in[14];
    const float* b2  = (const float*)d_in[15];
    float* out = (float*)d_out;

    char* W = (char*)d_ws;
    ushort_t* Vbf      = (ushort_t*)(W);               // 32 MB
    float*    scoreacc = (float*)(W + 33554432);       // 512 KB
    float*    probs    = (float*)(W + 34078720);       // 128 KB
    char* wbase = W + 34209792;
    ushort_t* Wqh = (ushort_t*)(wbase);
    ushort_t* Wql = (ushort_t*)(wbase + 32768);
    ushort_t* Wkh = (ushort_t*)(wbase + 65536);
    ushort_t* Wkl = (ushort_t*)(wbase + 98304);
    ushort_t* Wvh = (ushort_t*)(wbase + 131072);
    ushort_t* Wvl = (ushort_t*)(wbase + 163840);
    ushort_t* W1t = (ushort_t*)(wbase + 196608);       // 128 KB
    ushort_t* W2t = (ushort_t*)(wbase + 327680);       // 128 KB
    ushort_t* Wot = (ushort_t*)(wbase + 458752);       // 32 KB

    dim3 blk(256);
    k_wcvt<<<96, blk, 0, stream>>>(W1, W2, Wo, Wq, Wk, Wv,
                                   W1t, W2t, Wot, Wqh, Wql, Wkh, Wkl, Wvh, Wvl);
    k_qkvs<<<2048, blk, 0, stream>>>(q, v, Wqh, Wql, Wkh, Wkl, Wvh, Wvl,
                                     bq, bk, bv, Vbf, scoreacc);
    k_medsoft<<<512, dim3(64), 0, stream>>>(scoreacc, probs);
    k_tail<<<2048, blk, 0, stream>>>(Vbf, probs, Wot, bo, W1t, b1, W2t, b2,
                                     lng, lnb, v, out);
}

// Round 6
// 177.918 us; speedup vs baseline: 1.5720x; 1.1287x over previous
//
#include <hip/hip_runtime.h>
#include <math.h>

// ============================================================================
// Cross-covariance transformer block.  Round 6:
//  - k_tail: 4 blocks/CU (launch_bounds(256,4), LDS 36.5 KB: bf16 probs tile
//    [32][72], FFN hidden sliced 4x128 so Hid=16KB aliases Vg), tanh-gelu
//    (~7 instr), native bf16 casts (v_cvt_pk), XCD-swizzled blockIdx.
//  - k_qkvs: drop Wv-lo MFMA pass; cast-based hi/lo split.
//  - k_medsoft: emits probs as bf16.
// ============================================================================

typedef __bf16 bf16x8 __attribute__((ext_vector_type(8)));
typedef float f32x4 __attribute__((ext_vector_type(4)));
typedef unsigned short u16x8 __attribute__((ext_vector_type(8)));
typedef unsigned int u32x2 __attribute__((ext_vector_type(2)));
typedef unsigned int u32x4 __attribute__((ext_vector_type(4)));
typedef unsigned short ushort_t;

static constexpr int  DM   = 128;
static constexpr long NTOK = 131072;                 // B*S = 32*4096
static constexpr float NORMF = 0.17677669529663687f; // 1/sqrt(32)

__device__ __forceinline__ unsigned short f2b(float x) {
    __bf16 b = (__bf16)x;                       // RNE; compiler pairs to cvt_pk
    return __builtin_bit_cast(unsigned short, b);
}
__device__ __forceinline__ float b2f(unsigned short h) {
    return __builtin_bit_cast(float, ((unsigned)h) << 16);
}
__device__ __forceinline__ float b2f_lo(unsigned u) {
    return __builtin_bit_cast(float, u << 16);
}
__device__ __forceinline__ float b2f_hi(unsigned u) {
    return __builtin_bit_cast(float, u & 0xffff0000u);
}
__device__ __forceinline__ unsigned pack2(float a, float b) {
    return (unsigned)f2b(a) | ((unsigned)f2b(b) << 16);
}
__device__ __forceinline__ f32x4 mfma16(bf16x8 a, bf16x8 b, f32x4 c) {
    return __builtin_amdgcn_mfma_f32_16x16x32_bf16(a, b, c, 0, 0, 0);
}
// [64][128] bf16 tile, 16B chunks XOR-swizzled by tok&7
__device__ __forceinline__ int xb_off(int tok, int chunk) {
    int c = (chunk & 8) | ((chunk ^ tok) & 7);
    return tok * 128 + c * 8;
}
// tanh-form gelu: x*sigmoid(x*(1.59577+0.0713548*x^2)); |dev from erf| ~3e-4
__device__ __forceinline__ float gelu_f(float x) {
    float x2 = x * x;
    float y = -x * fmaf(0.0713548162f, x2, 1.5957691216f);
    float e = __expf(y);
    return x * __builtin_amdgcn_rcpf(1.0f + e);
}

// ---------------------------------------------------------------------------
// k_wcvt: weights -> MFMA-A-fragment-linear bf16 (W1/W2/Wo single, Wq/Wk/Wv
// hi/lo split).  A-frag: value = W[k][m], m = ot*16+lr, k = ks*32+lg*8+j.
// ---------------------------------------------------------------------------
__global__ __launch_bounds__(256)
void k_wcvt(const float* __restrict__ W1, const float* __restrict__ W2,
            const float* __restrict__ Wo, const float* __restrict__ Wq,
            const float* __restrict__ Wk, const float* __restrict__ Wv,
            ushort_t* __restrict__ W1t, ushort_t* __restrict__ W2t,
            ushort_t* __restrict__ Wot,
            ushort_t* __restrict__ Wqh, ushort_t* __restrict__ Wql,
            ushort_t* __restrict__ Wkh, ushort_t* __restrict__ Wkl,
            ushort_t* __restrict__ Wvh, ushort_t* __restrict__ Wvl)
{
    int frag = blockIdx.x * 4 + (threadIdx.x >> 6);
    int l = threadIdx.x & 63;
    int lr = l & 15, lg = l >> 4;
    u16x8 v;
    if (frag < 128) {                       // W1t: 32 hcol-tiles x 4 k-steps
        int ht = frag >> 2, ks = frag & 3;
        #pragma unroll
        for (int j = 0; j < 8; ++j)
            v[j] = f2b(W1[(ks * 32 + lg * 8 + j) * 512 + ht * 16 + lr]);
        *(u16x8*)(W1t + ((long)frag * 64 + l) * 8) = v;
    } else if (frag < 256) {                // W2t: 8 oc-tiles x 16 k-steps
        int f = frag - 128;
        int ot = f >> 4, ks = f & 15;
        #pragma unroll
        for (int j = 0; j < 8; ++j)
            v[j] = f2b(W2[(ks * 32 + lg * 8 + j) * 128 + ot * 16 + lr]);
        *(u16x8*)(W2t + ((long)f * 64 + l) * 8) = v;
    } else if (frag < 288) {                // Wot: 8 oc-tiles x 4 k-steps
        int f = frag - 256;
        int ot = f >> 2, ks = f & 3;
        #pragma unroll
        for (int j = 0; j < 8; ++j)
            v[j] = f2b(Wo[(ks * 32 + lg * 8 + j) * 128 + ot * 16 + lr]);
        *(u16x8*)(Wot + ((long)f * 64 + l) * 8) = v;
    } else {                                // Wq/Wk/Wv hi+lo, 32 frags each
        int f = frag - 288;
        const float* S = (f < 32) ? Wq : (f < 64) ? Wk : Wv;
        ushort_t* dh = (f < 32) ? Wqh : (f < 64) ? Wkh : Wvh;
        ushort_t* dl = (f < 32) ? Wql : (f < 64) ? Wkl : Wvl;
        int fl = f & 31, ot = fl >> 2, ks = fl & 3;
        u16x8 vh, vl;
        #pragma unroll
        for (int j = 0; j < 8; ++j) {
            float x = S[(ks * 32 + lg * 8 + j) * 128 + ot * 16 + lr];
            __bf16 bh = (__bf16)x;
            vh[j] = __builtin_bit_cast(unsigned short, bh);
            vl[j] = f2b(x - (float)bh);
        }
        *(u16x8*)(dh + ((long)fl * 64 + l) * 8) = vh;
        *(u16x8*)(dl + ((long)fl * 64 + l) * 8) = vl;
    }
}

// ---------------------------------------------------------------------------
// k_qkvs: 64 tokens/block.  Split-bf16 MFMA for Q (from v), K (3-pass), V
// (2-pass); 8-group normalize Q,K; partial scores -> scoreacc[block][64];
// V (bf16) -> global via LDS transpose.
// ---------------------------------------------------------------------------
__global__ __launch_bounds__(256, 2)
void k_qkvs(const float* __restrict__ qin, const float* __restrict__ vin,
            const ushort_t* __restrict__ Wqh, const ushort_t* __restrict__ Wql,
            const ushort_t* __restrict__ Wkh, const ushort_t* __restrict__ Wkl,
            const ushort_t* __restrict__ Wvh, const ushort_t* __restrict__ Wvl,
            const float* __restrict__ bq, const float* __restrict__ bk,
            const float* __restrict__ bv,
            ushort_t* __restrict__ Vbf, float* __restrict__ scoreacc)
{
    __shared__ __align__(16) char smem[65536];
    ushort_t* vhi = (ushort_t*)smem;            // [64][128] swz  (input v)
    ushort_t* vlo = vhi + 8192;
    ushort_t* qhi = vlo + 8192;                 // (input q)
    ushort_t* qlo = qhi + 8192;
    ushort_t* Vt  = (ushort_t*)smem;            // alias (16 KB) after phases
    float*    red = (float*)(smem + 16384);     // [16][33] alias

    const int tid = threadIdx.x;
    const int w = tid >> 6, l = tid & 63;
    const int lr = l & 15, lg = l >> 4;
    const long tok0 = (long)blockIdx.x * 64;

    // ---- stage inputs, split hi/lo ----
    #pragma unroll
    for (int i = 0; i < 4; ++i) {
        int e = tid + i * 256;
        int tok = e >> 4, c = e & 15;
        long base = (tok0 + tok) * DM + c * 8;
        int xo = xb_off(tok, c);
        {
            float4 a0 = *(const float4*)(vin + base);
            float4 a1 = *(const float4*)(vin + base + 4);
            float xs[8] = {a0.x, a0.y, a0.z, a0.w, a1.x, a1.y, a1.z, a1.w};
            u16x8 hi, lo;
            #pragma unroll
            for (int jj = 0; jj < 8; ++jj) {
                __bf16 bh = (__bf16)xs[jj];
                hi[jj] = __builtin_bit_cast(unsigned short, bh);
                lo[jj] = f2b(xs[jj] - (float)bh);
            }
            *(u16x8*)(vhi + xo) = hi;
            *(u16x8*)(vlo + xo) = lo;
        }
        {
            float4 a0 = *(const float4*)(qin + base);
            float4 a1 = *(const float4*)(qin + base + 4);
            float xs[8] = {a0.x, a0.y, a0.z, a0.w, a1.x, a1.y, a1.z, a1.w};
            u16x8 hi, lo;
            #pragma unroll
            for (int jj = 0; jj < 8; ++jj) {
                __bf16 bh = (__bf16)xs[jj];
                hi[jj] = __builtin_bit_cast(unsigned short, bh);
                lo[jj] = f2b(xs[jj] - (float)bh);
            }
            *(u16x8*)(qhi + xo) = hi;
            *(u16x8*)(qlo + xo) = lo;
        }
    }
    __syncthreads();

    // ---- Q phase (input v) ----
    float qv[2][4][4];
    {
        f32x4 acc[2][4];
        #pragma unroll
        for (int ot = 0; ot < 2; ++ot)
            #pragma unroll
            for (int tt = 0; tt < 4; ++tt) acc[ot][tt] = (f32x4){0,0,0,0};
        #pragma unroll
        for (int ks = 0; ks < 4; ++ks) {
            bf16x8 wh[2], wl[2];
            #pragma unroll
            for (int ot = 0; ot < 2; ++ot) {
                int fi = (((w * 2 + ot) * 4 + ks) * 64 + l) * 8;
                wh[ot] = *(const bf16x8*)(Wqh + fi);
                wl[ot] = *(const bf16x8*)(Wql + fi);
            }
            #pragma unroll
            for (int tt = 0; tt < 4; ++tt) {
                int xo = xb_off(tt * 16 + lr, ks * 4 + lg);
                bf16x8 xh = *(const bf16x8*)(vhi + xo);
                bf16x8 xl = *(const bf16x8*)(vlo + xo);
                #pragma unroll
                for (int ot = 0; ot < 2; ++ot) {
                    acc[ot][tt] = mfma16(wh[ot], xh, acc[ot][tt]);
                    acc[ot][tt] = mfma16(wh[ot], xl, acc[ot][tt]);
                    acc[ot][tt] = mfma16(wl[ot], xh, acc[ot][tt]);
                }
            }
        }
        #pragma unroll
        for (int ot = 0; ot < 2; ++ot) {
            f32x4 bqv = *(const f32x4*)(bq + w * 32 + ot * 16 + lg * 4);
            #pragma unroll
            for (int tt = 0; tt < 4; ++tt) {
                float s2 = 0.f;
                #pragma unroll
                for (int r = 0; r < 4; ++r) {
                    float x = acc[ot][tt][r] + bqv[r];
                    qv[ot][tt][r] = x;
                    s2 = fmaf(x, x, s2);
                }
                s2 += __shfl_xor(s2, 16);
                float inv = 1.0f / fmaxf(sqrtf(s2), 1e-12f);
                #pragma unroll
                for (int r = 0; r < 4; ++r) qv[ot][tt][r] *= inv;
            }
        }
    }

    // ---- K (3-pass) + V (2-pass) + incremental score accumulation ----
    float vv[2][4][4];
    float part[4][8];
    #pragma unroll
    for (int r = 0; r < 4; ++r)
        #pragma unroll
        for (int e = 0; e < 8; ++e) part[r][e] = 0.f;
    {
        f32x4 acck[2][4], accv[2][4];
        #pragma unroll
        for (int ot = 0; ot < 2; ++ot)
            #pragma unroll
            for (int tt = 0; tt < 4; ++tt) {
                acck[ot][tt] = (f32x4){0,0,0,0};
                accv[ot][tt] = (f32x4){0,0,0,0};
            }
        #pragma unroll
        for (int ks = 0; ks < 4; ++ks) {
            bf16x8 whk[2], wlk[2], whv[2];
            #pragma unroll
            for (int ot = 0; ot < 2; ++ot) {
                int fi = (((w * 2 + ot) * 4 + ks) * 64 + l) * 8;
                whk[ot] = *(const bf16x8*)(Wkh + fi);
                wlk[ot] = *(const bf16x8*)(Wkl + fi);
                whv[ot] = *(const bf16x8*)(Wvh + fi);
            }
            #pragma unroll
            for (int tt = 0; tt < 4; ++tt) {
                int xo = xb_off(tt * 16 + lr, ks * 4 + lg);
                bf16x8 xh = *(const bf16x8*)(qhi + xo);
                bf16x8 xl = *(const bf16x8*)(qlo + xo);
                #pragma unroll
                for (int ot = 0; ot < 2; ++ot) {
                    acck[ot][tt] = mfma16(whk[ot], xh, acck[ot][tt]);
                    acck[ot][tt] = mfma16(whk[ot], xl, acck[ot][tt]);
                    acck[ot][tt] = mfma16(wlk[ot], xh, acck[ot][tt]);
                    accv[ot][tt] = mfma16(whv[ot], xh, accv[ot][tt]);
                    accv[ot][tt] = mfma16(whv[ot], xl, accv[ot][tt]);
                }
            }
        }
        const int h0 = (lg & 1) * 4;
        #pragma unroll
        for (int ot = 0; ot < 2; ++ot) {
            f32x4 bkv = *(const f32x4*)(bk + w * 32 + ot * 16 + lg * 4);
            f32x4 bvv = *(const f32x4*)(bv + w * 32 + ot * 16 + lg * 4);
            #pragma unroll
            for (int tt = 0; tt < 4; ++tt) {
                float kq[4];
                float s2 = 0.f;
                #pragma unroll
                for (int r = 0; r < 4; ++r) {
                    float x = acck[ot][tt][r] + bkv[r];
                    kq[r] = x;
                    s2 = fmaf(x, x, s2);
                    vv[ot][tt][r] = accv[ot][tt][r] + bvv[r];
                }
                s2 += __shfl_xor(s2, 16);
                float inv = 1.0f / fmaxf(sqrtf(s2), 1e-12f);
                #pragma unroll
                for (int r = 0; r < 4; ++r) kq[r] *= inv;
                float ko[4];
                #pragma unroll
                for (int r = 0; r < 4; ++r) ko[r] = __shfl_xor(kq[r], 16);
                float ke[8];
                #pragma unroll
                for (int r = 0; r < 4; ++r) {
                    ke[h0 + r] = kq[r];
                    ke[(h0 ^ 4) + r] = ko[r];
                }
                #pragma unroll
                for (int r = 0; r < 4; ++r)
                    #pragma unroll
                    for (int e = 0; e < 8; ++e)
                        part[r][e] = fmaf(qv[ot][tt][r], ke[e], part[r][e]);
            }
        }
    }
    // reduce partials over lr lanes (bits 0..3)
    #pragma unroll
    for (int r = 0; r < 4; ++r)
        #pragma unroll
        for (int e = 0; e < 8; ++e) {
            float p = part[r][e];
            p += __shfl_xor(p, 1);
            p += __shfl_xor(p, 2);
            p += __shfl_xor(p, 4);
            p += __shfl_xor(p, 8);
            part[r][e] = p;
        }
    __syncthreads();   // x-tiles fully consumed; alias regions now writable

    // V regs -> Vt (swizzled bf16 [64][128])
    #pragma unroll
    for (int ot = 0; ot < 2; ++ot) {
        int oc0 = w * 32 + ot * 16 + lg * 4;
        int ch = oc0 >> 3;
        #pragma unroll
        for (int tt = 0; tt < 4; ++tt) {
            int tok = tt * 16 + lr;
            int cz = (ch & 8) | ((ch ^ tok) & 7);
            u32x2 pk = {pack2(vv[ot][tt][0], vv[ot][tt][1]),
                        pack2(vv[ot][tt][2], vv[ot][tt][3])};
            *(u32x2*)(Vt + tok * 128 + cz * 8 + (oc0 & 7)) = pk;
        }
    }
    if (lr == 0) {
        #pragma unroll
        for (int r = 0; r < 4; ++r)
            #pragma unroll
            for (int e = 0; e < 8; ++e)
                red[(w * 4 + lg) * 33 + r * 8 + e] = part[r][e];
    }
    __syncthreads();

    // coalesced V store
    #pragma unroll
    for (int i = 0; i < 4; ++i) {
        int e = tid + i * 256;
        int tok = e >> 4, c = e & 15;
        int cz = (c & 8) | ((c ^ tok) & 7);
        u16x8 val = *(const u16x8*)(Vt + tok * 128 + cz * 8);
        *(u16x8*)(Vbf + (tok0 + tok) * DM + c * 8) = val;
    }
    // final score partial for this block (deterministic slot per block)
    if (tid < 64) {
        int d = tid >> 3, e = tid & 7;
        int par = d >> 2, r = d & 3;
        float s = 0.f;
        #pragma unroll
        for (int ww = 0; ww < 4; ++ww)
            s += red[(ww * 4 + par) * 33 + r * 8 + e] +
                 red[(ww * 4 + par + 2) * 33 + r * 8 + e];
        scoreacc[(long)blockIdx.x * 64 + tid] = s;
    }
}

// ---------------------------------------------------------------------------
// k_medsoft: per chunk: sum 4 block-partials, *NORMF, lower-median strict
// mask, softmax -> probs (bf16) [p][8][8].
// ---------------------------------------------------------------------------
__global__ __launch_bounds__(64)
void k_medsoft(const float* __restrict__ scoreacc, ushort_t* __restrict__ probsb)
{
    __shared__ float sc[64], pl[64];
    const int p = blockIdx.x, tid = threadIdx.x;
    const float* s0 = scoreacc + (long)p * 256;
    sc[tid] = (s0[tid] + s0[64 + tid] + s0[128 + tid] + s0[192 + tid]) * NORMF;
    __syncthreads();
    if (tid < 8) {
        float row[8], st[8];
        #pragma unroll
        for (int e = 0; e < 8; ++e) { row[e] = sc[tid * 8 + e]; st[e] = row[e]; }
        for (int a = 1; a < 8; ++a) {
            float v = st[a]; int b = a - 1;
            while (b >= 0 && st[b] > v) { st[b + 1] = st[b]; --b; }
            st[b + 1] = v;
        }
        float med = st[3];
        float mv[8]; float mx = -3.0e38f;
        #pragma unroll
        for (int e = 0; e < 8; ++e) {
            mv[e] = (row[e] - med > 0.f) ? row[e] : -1e30f;
            mx = fmaxf(mx, mv[e]);
        }
        float z = 0.f, ex[8];
        #pragma unroll
        for (int e = 0; e < 8; ++e) { ex[e] = expf(mv[e] - mx); z += ex[e]; }
        float iz = 1.f / z;
        #pragma unroll
        for (int e = 0; e < 8; ++e) pl[tid * 8 + e] = ex[e] * iz;
    }
    __syncthreads();
    probsb[(long)p * 64 + tid] = f2b(pl[tid]);
}

// ---------------------------------------------------------------------------
// k_tail: fused AO-gather + Wo + LN1 + FFN + LN2 + v.  64 tok2/block.
// LDS 36.5 KB -> 4 blocks/CU with VGPR<=128 (launch_bounds(256,4)).
// ---------------------------------------------------------------------------
__global__ __launch_bounds__(256, 4)
void k_tail(const ushort_t* __restrict__ Vbf, const ushort_t* __restrict__ Pb,
            const ushort_t* __restrict__ Wot, const float* __restrict__ bo,
            const ushort_t* __restrict__ W1t, const float* __restrict__ b1,
            const ushort_t* __restrict__ W2t, const float* __restrict__ b2,
            const float* __restrict__ lng, const float* __restrict__ lnb,
            const float* __restrict__ vres, float* __restrict__ out)
{
    __shared__ __align__(16) char smem[37376];
    ushort_t* Xb  = (ushort_t*)smem;                 // 16 KB attn->h tile
    ushort_t* Vg  = (ushort_t*)(smem + 16384);       // 16 KB V gather
    ushort_t* Plb = (ushort_t*)(smem + 32768);       // [32][72] bf16 probs
    ushort_t* Hid = (ushort_t*)(smem + 16384);       // 16 KB (alias Vg)
    float* pS  = (float*)(smem + 32768);             // alias Plb (post-AO)
    float* pQ  = pS + 256;
    float* muS = pQ + 256;
    float* rsS = muS + 64;

    const int tid = threadIdx.x;
    const int w = tid >> 6, l = tid & 63;
    const int lr = l & 15, lg = l >> 4;
    // XCD swizzle: 2048 blocks, 8 XCDs -> 256 consecutive tiles per XCD
    const int wid = ((blockIdx.x & 7) << 8) | (blockIdx.x >> 3);
    const long T0 = (long)wid * 64;
    const int g  = (int)(T0 >> 13);
    const int r0 = (int)((T0 & 8191) >> 5);

    // ---- stage probs (bf16) for this g's 32 chunks ----
    {
        int e = tid * 8;
        u16x8 pv = *(const u16x8*)(Pb + (long)g * 2048 + e);
        *(u16x8*)(Plb + (e >> 6) * 72 + (e & 63)) = pv;
    }
    // ---- gather the 64 V rows this tile consumes ----
    #pragma unroll
    for (int i = 0; i < 4; ++i) {
        int e = tid + i * 256;
        int ri = e >> 4, c = e & 15;
        int hb = ri >> 5, bm = (ri >> 1) & 15, rr = ri & 1;
        long t = ((long)(g * 32 + hb * 16 + bm)) * 256 + r0 + rr;
        u16x8 val = *(const u16x8*)(Vbf + t * DM + c * 8);
        int cz = (c & 8) | ((c ^ (ri >> 1)) & 7);
        *(u16x8*)(Vg + ri * 128 + cz * 8) = val;
    }
    __syncthreads();

    // ---- AO: attn[ti][bm*8+d] = sum_e P[p][d][e] * Vg -> Xb (bf16 swz) ----
    #pragma unroll
    for (int i = 0; i < 4; ++i) {
        int e = tid + i * 256;
        int ti = e >> 4, bm = e & 15;
        int jj = (ti & 31) >> 1, hb = ti & 1, rr = ti >> 5;
        int ri = hb * 32 + bm * 2 + rr;
        int cz = (jj & 8) | ((jj ^ (ri >> 1)) & 7);
        u16x8 v8 = *(const u16x8*)(Vg + ri * 128 + cz * 8);
        float vf[8];
        #pragma unroll
        for (int e2 = 0; e2 < 8; ++e2) vf[e2] = b2f(v8[e2]);
        const ushort_t* pp = Plb + (hb * 16 + bm) * 72;
        float sd[8];
        #pragma unroll
        for (int d = 0; d < 8; ++d) {
            u16x8 pr = *(const u16x8*)(pp + d * 8);
            float s = 0.f;
            #pragma unroll
            for (int e2 = 0; e2 < 8; ++e2) s = fmaf(b2f(pr[e2]), vf[e2], s);
            sd[d] = s;
        }
        u32x4 po = {pack2(sd[0], sd[1]), pack2(sd[2], sd[3]),
                    pack2(sd[4], sd[5]), pack2(sd[6], sd[7])};
        *(u32x4*)(Xb + xb_off(ti, bm)) = po;
    }
    __syncthreads();

    // ---- Wo GEMM + LN1 (h transient in registers, then -> Xb as bf16) ----
    f32x4 g4[2], bb4[2];
    #pragma unroll
    for (int ot = 0; ot < 2; ++ot) {
        int oc0 = w * 32 + ot * 16 + lg * 4;
        g4[ot]  = *(const f32x4*)(lng + oc0);
        bb4[ot] = *(const f32x4*)(lnb + oc0);
    }
    float vals[4][2][4];
    float sums[4], sqs[4];
    {
        bf16x8 aw[2][4];
        #pragma unroll
        for (int ot = 0; ot < 2; ++ot)
            #pragma unroll
            for (int ks = 0; ks < 4; ++ks)
                aw[ot][ks] = *(const bf16x8*)(Wot +
                    ((long)((w * 2 + ot) * 4 + ks) * 64 + l) * 8);
        f32x4 bov[2];
        #pragma unroll
        for (int ot = 0; ot < 2; ++ot)
            bov[ot] = *(const f32x4*)(bo + w * 32 + ot * 16 + lg * 4);

        #pragma unroll
        for (int tt = 0; tt < 4; ++tt) {
            f32x4 acc0 = (f32x4){0,0,0,0}, acc1 = (f32x4){0,0,0,0};
            int tok = tt * 16 + lr;
            #pragma unroll
            for (int ks = 0; ks < 4; ++ks) {
                bf16x8 bfrag = *(const bf16x8*)(Xb + xb_off(tok, ks * 4 + lg));
                acc0 = mfma16(aw[0][ks], bfrag, acc0);
                acc1 = mfma16(aw[1][ks], bfrag, acc1);
            }
            long gtok = T0 + tok;
            float s = 0.f, q = 0.f;
            #pragma unroll
            for (int ot = 0; ot < 2; ++ot) {
                int oc0 = w * 32 + ot * 16 + lg * 4;
                f32x4 xv = *(const f32x4*)(vres + gtok * DM + oc0);
                #pragma unroll
                for (int r = 0; r < 4; ++r) {
                    float av = ot ? acc1[r] : acc0[r];
                    float vvv = av + bov[ot][r] + xv[r];
                    vals[tt][ot][r] = vvv;
                    s += vvv; q = fmaf(vvv, vvv, q);
                }
            }
            sums[tt] = s; sqs[tt] = q;
        }
    }
    #pragma unroll
    for (int tt = 0; tt < 4; ++tt) {
        sums[tt] += __shfl_xor(sums[tt], 16);
        sums[tt] += __shfl_xor(sums[tt], 32);
        sqs[tt]  += __shfl_xor(sqs[tt], 16);
        sqs[tt]  += __shfl_xor(sqs[tt], 32);
    }
    #pragma unroll
    for (int tt = 0; tt < 4; ++tt)
        if (lg == tt) { pS[(w * 4 + tt) * 16 + lr] = sums[tt];
                        pQ[(w * 4 + tt) * 16 + lr] = sqs[tt]; }
    __syncthreads();
    if (tid < 64) {
        float s = pS[tid] + pS[64 + tid] + pS[128 + tid] + pS[192 + tid];
        float q = pQ[tid] + pQ[64 + tid] + pQ[128 + tid] + pQ[192 + tid];
        float mu = s * 0.0078125f;
        float var = q * 0.0078125f - mu * mu;
        muS[tid] = mu;
        rsS[tid] = rsqrtf(var + 1e-5f);
    }
    __syncthreads();
    // finalize h -> Xb as bf16 (vals dead after; FFN + LN2 read Xb)
    #pragma unroll
    for (int tt = 0; tt < 4; ++tt) {
        int tok = tt * 16 + lr;
        float mu = muS[tok], rs = rsS[tok];
        #pragma unroll
        for (int ot = 0; ot < 2; ++ot) {
            int oc0 = w * 32 + ot * 16 + lg * 4;
            float hf[4];
            #pragma unroll
            for (int r = 0; r < 4; ++r)
                hf[r] = (vals[tt][ot][r] - mu) * rs * g4[ot][r] + bb4[ot][r];
            int ch = oc0 >> 3;
            int cz = (ch & 8) | ((ch ^ tok) & 7);
            u32x2 pk = {pack2(hf[0], hf[1]), pack2(hf[2], hf[3])};
            *(u32x2*)(Xb + tok * 128 + cz * 8 + (oc0 & 7)) = pk;
        }
    }
    __syncthreads();

    // ---- FFN: 4 hidden slices of 128 (Hid = 16 KB, aliases Vg) ----
    f32x4 oacc[4][2];
    #pragma unroll
    for (int tt = 0; tt < 4; ++tt) {
        oacc[tt][0] = (f32x4){0,0,0,0};
        oacc[tt][1] = (f32x4){0,0,0,0};
    }
    for (int sl = 0; sl < 4; ++sl) {
        // stage 1: Hid-slice = gelu(X@W1_sl + b1_sl), transposed D
        bf16x8 a1[2][4];
        f32x4 b1v[2];
        #pragma unroll
        for (int hh = 0; hh < 2; ++hh) {
            #pragma unroll
            for (int ks = 0; ks < 4; ++ks)
                a1[hh][ks] = *(const bf16x8*)(W1t +
                    ((long)((sl * 8 + w * 2 + hh) * 4 + ks) * 64 + l) * 8);
            b1v[hh] = *(const f32x4*)(b1 + (sl * 8 + w * 2 + hh) * 16 + lg * 4);
        }
        #pragma unroll
        for (int tt = 0; tt < 4; ++tt) {
            f32x4 acc[2] = {(f32x4){0,0,0,0}, (f32x4){0,0,0,0}};
            int tok = tt * 16 + lr;
            #pragma unroll
            for (int ks = 0; ks < 4; ++ks) {
                bf16x8 bfrag = *(const bf16x8*)(Xb + xb_off(tok, ks * 4 + lg));
                acc[0] = mfma16(a1[0][ks], bfrag, acc[0]);
                acc[1] = mfma16(a1[1][ks], bfrag, acc[1]);
            }
            #pragma unroll
            for (int hh = 0; hh < 2; ++hh) {
                float gg[4];
                #pragma unroll
                for (int r = 0; r < 4; ++r)
                    gg[r] = gelu_f(acc[hh][r] + b1v[hh][r]);
                int hc0 = w * 32 + hh * 16 + lg * 4;
                int ch = hc0 >> 3;
                int cz = (ch & 8) | ((ch ^ tok) & 7);
                u32x2 pk = {pack2(gg[0], gg[1]), pack2(gg[2], gg[3])};
                *(u32x2*)(Hid + tok * 128 + cz * 8 + (hc0 & 7)) = pk;
            }
        }
        __syncthreads();
        // stage 2: accumulate slice
        bf16x8 a2[2][4];
        #pragma unroll
        for (int op = 0; op < 2; ++op)
            #pragma unroll
            for (int kl = 0; kl < 4; ++kl)
                a2[op][kl] = *(const bf16x8*)(W2t +
                    ((long)((w * 2 + op) * 16 + sl * 4 + kl) * 64 + l) * 8);
        #pragma unroll
        for (int tt = 0; tt < 4; ++tt) {
            int tok = tt * 16 + lr;
            #pragma unroll
            for (int kl = 0; kl < 4; ++kl) {
                bf16x8 bfrag = *(const bf16x8*)(Hid + xb_off(tok, kl * 4 + lg));
                oacc[tt][0] = mfma16(a2[0][kl], bfrag, oacc[tt][0]);
                oacc[tt][1] = mfma16(a2[1][kl], bfrag, oacc[tt][1]);
            }
        }
        __syncthreads();
    }

    // ---- LN2 epilogue: out = LN(h + ffn) + v, h re-read from Xb (bf16) ----
    f32x4 b2v[2];
    #pragma unroll
    for (int ot = 0; ot < 2; ++ot)
        b2v[ot] = *(const f32x4*)(b2 + w * 32 + ot * 16 + lg * 4);
    #pragma unroll
    for (int tt = 0; tt < 4; ++tt) {
        int tok = tt * 16 + lr;
        float s = 0.f, q = 0.f;
        #pragma unroll
        for (int ot = 0; ot < 2; ++ot) {
            int oc0 = w * 32 + ot * 16 + lg * 4;
            int ch = oc0 >> 3;
            int cz = (ch & 8) | ((ch ^ tok) & 7);
            u32x2 hp = *(const u32x2*)(Xb + tok * 128 + cz * 8 + (oc0 & 7));
            float hr[4] = {b2f_lo(hp[0]), b2f_hi(hp[0]),
                           b2f_lo(hp[1]), b2f_hi(hp[1])};
            #pragma unroll
            for (int r = 0; r < 4; ++r) {
                float vvv = oacc[tt][ot][r] + b2v[ot][r] + hr[r];
                s += vvv; q = fmaf(vvv, vvv, q);
            }
        }
        sums[tt] = s; sqs[tt] = q;
    }
    #pragma unroll
    for (int tt = 0; tt < 4; ++tt) {
        sums[tt] += __shfl_xor(sums[tt], 16);
        sums[tt] += __shfl_xor(sums[tt], 32);
        sqs[tt]  += __shfl_xor(sqs[tt], 16);
        sqs[tt]  += __shfl_xor(sqs[tt], 32);
    }
    #pragma unroll
    for (int tt = 0; tt < 4; ++tt)
        if (lg == tt) { pS[(w * 4 + tt) * 16 + lr] = sums[tt];
                        pQ[(w * 4 + tt) * 16 + lr] = sqs[tt]; }
    __syncthreads();
    if (tid < 64) {
        float s = pS[tid] + pS[64 + tid] + pS[128 + tid] + pS[192 + tid];
        float q = pQ[tid] + pQ[64 + tid] + pQ[128 + tid] + pQ[192 + tid];
        float mu = s * 0.0078125f;
        float var = q * 0.0078125f - mu * mu;
        muS[tid] = mu;
        rsS[tid] = rsqrtf(var + 1e-5f);
    }
    __syncthreads();
    #pragma unroll
    for (int tt = 0; tt < 4; ++tt) {
        int tok = tt * 16 + lr;
        long gtok = T0 + tok;
        float mu = muS[tok], rs = rsS[tok];
        #pragma unroll
        for (int ot = 0; ot < 2; ++ot) {
            int oc0 = w * 32 + ot * 16 + lg * 4;
            int ch = oc0 >> 3;
            int cz = (ch & 8) | ((ch ^ tok) & 7);
            u32x2 hp = *(const u32x2*)(Xb + tok * 128 + cz * 8 + (oc0 & 7));
            float hr[4] = {b2f_lo(hp[0]), b2f_hi(hp[0]),
                           b2f_lo(hp[1]), b2f_hi(hp[1])};
            f32x4 vv4 = *(const f32x4*)(vres + gtok * DM + oc0);
            f32x4 o;
            #pragma unroll
            for (int r = 0; r < 4; ++r) {
                float vvv = oacc[tt][ot][r] + b2v[ot][r] + hr[r];
                o[r] = (vvv - mu) * rs * g4[ot][r] + bb4[ot][r] + vv4[r];
            }
            *(f32x4*)(out + gtok * DM + oc0) = o;
        }
    }
}

// ---------------------------------------------------------------------------
extern "C" void kernel_launch(void* const* d_in, const int* in_sizes, int n_in,
                              void* d_out, int out_size, void* d_ws, size_t ws_size,
                              hipStream_t stream)
{
    const float* q   = (const float*)d_in[0];
    const float* v   = (const float*)d_in[1];
    const float* Wq  = (const float*)d_in[2];
    const float* bq  = (const float*)d_in[3];
    const float* Wk  = (const float*)d_in[4];
    const float* bk  = (const float*)d_in[5];
    const float* Wv  = (const float*)d_in[6];
    const float* bv  = (const float*)d_in[7];
    const float* Wo  = (const float*)d_in[8];
    const float* bo  = (const float*)d_in[9];
    const float* lng = (const float*)d_in[10];
    const float* lnb = (const float*)d_in[11];
    const float* W1  = (const float*)d_in[12];
    const float* b1  = (const float*)d_in[13];
    const float* W2  = (const float*)d_in[14];
    const float* b2  = (const float*)d_in[15];
    float* out = (float*)d_out;

    char* W = (char*)d_ws;
    ushort_t* Vbf      = (ushort_t*)(W);               // 32 MB
    float*    scoreacc = (float*)(W + 33554432);       // 512 KB
    ushort_t* probsb   = (ushort_t*)(W + 34078720);    // 64 KB (bf16)
    char* wbase = W + 34209792;
    ushort_t* Wqh = (ushort_t*)(wbase);
    ushort_t* Wql = (ushort_t*)(wbase + 32768);
    ushort_t* Wkh = (ushort_t*)(wbase + 65536);
    ushort_t* Wkl = (ushort_t*)(wbase + 98304);
    ushort_t* Wvh = (ushort_t*)(wbase + 131072);
    ushort_t* Wvl = (ushort_t*)(wbase + 163840);
    ushort_t* W1t = (ushort_t*)(wbase + 196608);       // 128 KB
    ushort_t* W2t = (ushort_t*)(wbase + 327680);       // 128 KB
    ushort_t* Wot = (ushort_t*)(wbase + 458752);       // 32 KB

    dim3 blk(256);
    k_wcvt<<<96, blk, 0, stream>>>(W1, W2, Wo, Wq, Wk, Wv,
                                   W1t, W2t, Wot, Wqh, Wql, Wkh, Wkl, Wvh, Wvl);
    k_qkvs<<<2048, blk, 0, stream>>>(q, v, Wqh, Wql, Wkh, Wkl, Wvh, Wvl,
                                     bq, bk, bv, Vbf, scoreacc);
    k_medsoft<<<512, dim3(64), 0, stream>>>(scoreacc, probsb);
    k_tail<<<2048, blk, 0, stream>>>(Vbf, probsb, Wot, bo, W1t, b1, W2t, b2,
                                     lng, lnb, v, out);
}